// Round 5
// baseline (320.748 us; speedup 1.0000x reference)
//
#include <hip/hip_runtime.h>
#include <hip/hip_bf16.h>
#include <cstdint>

// B=4, S=2048, D=1024, NH=16, DK=64. Inputs fp32, output fp32.
// Pipeline:
//   convert: xb = bf16(x); weights -> bf16 in ONE launch (fast path)
//   qkv_gemm (fused, 1536 blocks): Q|K plain bf16 stores; V -> LDS-transpose
//            (XOR-swizzled, stride 128 -> LDS exactly 32 KiB) -> Vt[1024][8192].
//   rope_table -> rope2 (Q scale=log2e/8 and K in one launch)
//   attn: causal flash, fixed-max exp2 softmax, S^T-MFMA; lsum via MFMA with
//         ones-B-frag; softmax fused into the mi-loop (register pressure!).
//   gemm_o: 128x64 tiles (1024 blocks), out = AO @ o_proj^T -> fp32
//
// R12 post-mortem: lacc-MFMA pushed attn VGPR 80->104, crossing the 102
// boundary (512/5): 5->4 blocks/CU, occupancy 27->17%, attn 81.5->108us.
// Cause: st[4][2] (32 VGPRs) live across the whole softmax phase + lacc(8)
// + ones8(4).
// R13: fuse exp2/mask/pack/lP-write into the per-mi loop -> only one mi's
// scores (8 VGPRs) live at a time; keep lacc-MFMA (saves 16 VALU adds/kt +
// the shuffle epilogue). Predict VGPR <=102 -> 5 blocks/CU restored, attn
// ~75us. Lesson stack: R11 = don't cap regs below natural; R13 = reduce
// natural pressure structurally.

typedef __attribute__((ext_vector_type(8))) short short8;
typedef __attribute__((ext_vector_type(4))) float float4v;

#define MFMA16(a, b, c) __builtin_amdgcn_mfma_f32_16x16x32_bf16((a), (b), (c), 0, 0, 0)

__device__ __forceinline__ void glds16(const void* g, void* l) {
    __builtin_amdgcn_global_load_lds(
        (const __attribute__((address_space(1))) void*)g,
        (__attribute__((address_space(3))) void*)l, 16, 0, 0);
}

__device__ __forceinline__ unsigned int pk2(float a, float b) {
    __hip_bfloat162 h = __float22bfloat162_rn(make_float2(a, b));  // v_cvt_pk_bf16_f32
    union { __hip_bfloat162 h; unsigned int u; } v; v.h = h;
    return v.u;
}

__device__ __forceinline__ unsigned short f2bf(float x) {
    union { float f; unsigned int u; } v; v.f = x;
    unsigned int r = (v.u + 0x7FFFu + ((v.u >> 16) & 1u)) >> 16;   // RNE
    return (unsigned short)r;
}

__device__ __forceinline__ float bf2f(unsigned short b) {
    union { unsigned int u; float f; } v; v.u = ((unsigned int)b) << 16;
    return v.f;
}

// 8 contiguous fp32 -> bf16 bits (packed converts)
__device__ __forceinline__ short8 load8f(const float* p) {
    const float4 f0 = *(const float4*)p;
    const float4 f1 = *(const float4*)(p + 4);
    union { short8 s; unsigned int u[4]; } r;
    r.u[0] = pk2(f0.x, f0.y);
    r.u[1] = pk2(f0.z, f0.w);
    r.u[2] = pk2(f1.x, f1.y);
    r.u[3] = pk2(f1.z, f1.w);
    return r.s;
}

// ---------------------------------------------------------------------------
__global__ __launch_bounds__(256) void convert_kernel(
    const float* __restrict__ in, __hip_bfloat16* __restrict__ out)
{
    const int idx = (blockIdx.x * 256 + threadIdx.x) * 8;
    *(short8*)(out + idx) = load8f(in + idx);
}

// 4 weight matrices (1M elems each) in one launch: 512 blocks per matrix.
__global__ __launch_bounds__(256) void convert4_kernel(
    const float* __restrict__ a, const float* __restrict__ b,
    const float* __restrict__ c, const float* __restrict__ d,
    __hip_bfloat16* __restrict__ oa, __hip_bfloat16* __restrict__ ob,
    __hip_bfloat16* __restrict__ oc, __hip_bfloat16* __restrict__ od)
{
    const int m = blockIdx.x >> 9;
    const float* in = (m == 0) ? a : (m == 1) ? b : (m == 2) ? c : d;
    __hip_bfloat16* out = (m == 0) ? oa : (m == 1) ? ob : (m == 2) ? oc : od;
    const int idx = ((blockIdx.x & 511) * 256 + threadIdx.x) * 8;
    *(short8*)(out + idx) = load8f(in + idx);
}

// ---------------------------------------------------------------------------
__global__ __launch_bounds__(256) void rope_table_kernel(float2* __restrict__ table)
{
    const int idx = blockIdx.x * 256 + threadIdx.x;   // 65536
    const int pos = idx >> 5, fi = idx & 31;
    const float f = exp2f(-(float)fi * (13.287712379549449f / 32.0f));
    float sn, cs;
    sincosf((float)pos * f, &sn, &cs);
    table[idx] = make_float2(cs, sn);
}

// ---------------------------------------------------------------------------
// Rope in place on Q and K [8192][1024] in one launch; pairs (2i,2i+1) per
// 64-dim head, pos=row%2048. Q half gets scale=log2e/8, K half 1.0.
// ---------------------------------------------------------------------------
__global__ __launch_bounds__(256) void rope2_kernel(
    __hip_bfloat16* __restrict__ Qp, __hip_bfloat16* __restrict__ Kp,
    const float2* __restrict__ table)
{
    const int sel = blockIdx.x >> 14;                 // 0 = Q, 1 = K
    __hip_bfloat16* T = sel ? Kp : Qp;
    const float scale = sel ? 1.0f : 0.18033688011112042f;
    const int idx = (blockIdx.x & 16383) * 256 + threadIdx.x;   // 8192*512
    const int r = idx >> 9;
    const int p = idx & 511;
    const int h = p >> 5, i = p & 31;
    const float2 cs = table[(r & 2047) * 32 + i];
    unsigned short* ptr = (unsigned short*)T + (int64_t)r * 1024 + h * 64 + 2 * i;
    const ushort2 xv = *(const ushort2*)ptr;
    const float x1 = bf2f(xv.x), x2 = bf2f(xv.y);
    const unsigned int o = pk2((x1 * cs.x - x2 * cs.y) * scale,
                               (x1 * cs.y + x2 * cs.x) * scale);
    *(unsigned int*)ptr = o;
}

// ---------------------------------------------------------------------------
// Fused QKV GEMM. A = xb [8192x1024] bf16 (glds16). B = {wq,wk,wv}[1024x1024]:
// BBF=1 -> bf16 glds16; BBF=0 -> fp32 packed register-convert.
// Q/K: plain bf16 store. V: XOR-swizzled LDS-transpose -> Vt coalesced.
// LDS = 128*128 halves = 32768 B. No min-waves hint (R11 lesson).
// ---------------------------------------------------------------------------
template<int BBF>
__global__ __launch_bounds__(256) void qkv_gemm(
    const __hip_bfloat16* __restrict__ Abf,
    const void* __restrict__ Wq, const void* __restrict__ Wk, const void* __restrict__ Wv,
    __hip_bfloat16* __restrict__ Qp, __hip_bfloat16* __restrict__ Kp,
    __hip_bfloat16* __restrict__ Vt)
{
    __shared__ unsigned short smem[128 * 128];   // 32768 B; staging uses [0..8191]

    const int K = 1024;
    const int bm = blockIdx.x / 24, bn = blockIdx.x % 24;
    const int widx = bn >> 3;              // 0=Q 1=K 2=V
    const int bcol0 = (bn & 7) * 128;
    const void* W = (widx == 0) ? Wq : (widx == 1) ? Wk : Wv;

    const int tid = threadIdx.x;
    const int wave = tid >> 6, lane = tid & 63;
    const int wm = (wave >> 1) * 64, wn = (wave & 1) * 64;
    const int m16 = lane & 15, quad = lane >> 4;

    const int lrow = lane >> 2, lcol = (lane & 3) * 8;   // glds map
    const int srow = tid >> 2, scol = (tid & 3) * 8;     // register-path map

    float4v acc[4][4] = {};

    for (int k0 = 0; k0 < K; k0 += 32) {
        short8 rb0, rb1;
        if (!BBF) {
            const float* Wf = (const float*)W;
            rb0 = load8f(Wf + (int64_t)(bcol0 + srow) * K + scol + k0);
            rb1 = load8f(Wf + (int64_t)(bcol0 + 64 + srow) * K + scol + k0);
        }
        __syncthreads();
        {
            const __hip_bfloat16* g = Abf + (int64_t)(bm * 128 + wave * 32 + lrow) * K + lcol + k0;
            glds16(g, &smem[wave * 1024]);
            glds16(g + (int64_t)16 * K, &smem[wave * 1024 + 512]);
        }
        if (BBF) {
            const __hip_bfloat16* g = (const __hip_bfloat16*)W +
                (int64_t)(bcol0 + wave * 32 + lrow) * K + lcol + k0;
            glds16(g, &smem[4096 + wave * 1024]);
            glds16(g + (int64_t)16 * K, &smem[4096 + wave * 1024 + 512]);
        } else {
            *(short8*)&smem[4096 + srow * 32 + scol] = rb0;
            *(short8*)&smem[4096 + (64 + srow) * 32 + scol] = rb1;
        }
        __syncthreads();

        short8 af[4], bf[4];
#pragma unroll
        for (int i = 0; i < 4; i++)
            af[i] = *(const short8*)&smem[(wm + i * 16 + m16) * 32 + quad * 8];
#pragma unroll
        for (int j = 0; j < 4; j++)
            bf[j] = *(const short8*)&smem[4096 + (wn + j * 16 + m16) * 32 + quad * 8];
#pragma unroll
        for (int i = 0; i < 4; i++)
#pragma unroll
            for (int j = 0; j < 4; j++)
                acc[i][j] = MFMA16(af[i], bf[j], acc[i][j]);
    }

    if (widx == 2) {
        // ---- V: transpose through LDS (XOR swizzle, stride 128) ----
        __syncthreads();
#pragma unroll
        for (int i = 0; i < 4; i++)
#pragma unroll
            for (int j = 0; j < 4; j++) {
                const int col = wn + j * 16 + m16;
                const int key = (col & 7) * 8;
#pragma unroll
                for (int r = 0; r < 4; r++) {
                    const int row = wm + i * 16 + quad * 4 + r;
                    smem[col * 128 + (row ^ key)] = f2bf(acc[i][j][r]);
                }
            }
        __syncthreads();
        const int dc = tid >> 4;          // 0..15
        const int seg = (tid & 15) * 8;   // 0..120 (mult of 8 -> XOR stays contiguous)
#pragma unroll
        for (int pass = 0; pass < 8; pass++) {
            const int dcol = pass * 16 + dc;
            const short8 v = *(const short8*)&smem[dcol * 128 + (seg ^ ((dcol & 7) * 8))];
            *(short8*)((unsigned short*)Vt + (int64_t)(bcol0 + dcol) * 8192 + bm * 128 + seg) = v;
        }
    } else {
        // ---- Q/K: plain store (C layout: col = lane&15, row = quad*4+r) ----
        __hip_bfloat16* dst = (widx == 0) ? Qp : Kp;
        const int row0 = bm * 128 + wm + quad * 4;
        const int col0 = bcol0 + wn + m16;
#pragma unroll
        for (int i = 0; i < 4; i++)
#pragma unroll
            for (int j = 0; j < 4; j++)
#pragma unroll
                for (int r = 0; r < 4; r++)
                    dst[(int64_t)(row0 + i * 16 + r) * 1024 + col0 + j * 16] =
                        __float2bfloat16(acc[i][j][r]);
    }
}

// ---------------------------------------------------------------------------
// Output GEMM: C[8192][1024] fp32 = A(bf16, glds16) * B^T; BBF as above.
// BM=128, BN=64 -> 1024 blocks (4/CU resident) for latency hiding.
// ---------------------------------------------------------------------------
template<int BBF>
__global__ __launch_bounds__(256) void gemm_o(
    const __hip_bfloat16* __restrict__ Abf, const void* __restrict__ B,
    float* __restrict__ C, int M, int N, int K)
{
    __shared__ __hip_bfloat16 lA[128 * 32];
    __shared__ __hip_bfloat16 lB[64 * 32];

    const int nb = N >> 6;
    const int bm = blockIdx.x / nb, bn = blockIdx.x % nb;
    const int tid = threadIdx.x;
    const int wave = tid >> 6, lane = tid & 63;
    const int wm = (wave >> 1) * 64, wn = (wave & 1) * 32;
    const int m16 = lane & 15, quad = lane >> 4;
    const int lrow = lane >> 2, lcol = (lane & 3) * 8;
    const int srow = tid >> 2, scol = (tid & 3) * 8;

    float4v acc[4][2] = {};

    for (int k0 = 0; k0 < K; k0 += 32) {
        short8 rb0;
        if (!BBF) {
            const float* Bf = (const float*)B;
            rb0 = load8f(Bf + (int64_t)(bn * 64 + srow) * K + scol + k0);
        }
        __syncthreads();
        {
            const __hip_bfloat16* g = Abf + (int64_t)(bm * 128 + wave * 32 + lrow) * K + lcol + k0;
            glds16(g, &lA[wave * 1024]);
            glds16(g + (int64_t)16 * K, &lA[wave * 1024 + 512]);
        }
        if (BBF) {
            // 4 waves x 16 rows each: lane>>2 = row 0..15, (lane&3)*8 = col
            glds16((const __hip_bfloat16*)B +
                   (int64_t)(bn * 64 + wave * 16 + (lane >> 2)) * K + lcol + k0,
                   &lB[wave * 512]);
        } else {
            *(short8*)&lB[srow * 32 + scol] = rb0;
        }
        __syncthreads();

        short8 af[4], bf[2];
#pragma unroll
        for (int i = 0; i < 4; i++)
            af[i] = *(const short8*)&lA[(wm + i * 16 + m16) * 32 + quad * 8];
#pragma unroll
        for (int j = 0; j < 2; j++)
            bf[j] = *(const short8*)&lB[(wn + j * 16 + m16) * 32 + quad * 8];
#pragma unroll
        for (int i = 0; i < 4; i++)
#pragma unroll
            for (int j = 0; j < 2; j++)
                acc[i][j] = MFMA16(af[i], bf[j], acc[i][j]);
    }

    const int row0 = bm * 128 + wm + quad * 4;
    const int col0 = bn * 64 + wn + m16;
#pragma unroll
    for (int i = 0; i < 4; i++)
#pragma unroll
        for (int j = 0; j < 2; j++)
#pragma unroll
            for (int r = 0; r < 4; r++)
                C[(int64_t)(row0 + i * 16 + r) * N + col0 + j * 16] = acc[i][j][r];
}

// ---------------------------------------------------------------------------
// Flash attention, causal, fixed-max softmax (Q pre-scaled by log2e/8;
// p = exp2(score)). Block = 4 waves x 32 Q rows = 128; Bc = 64.
// S^T-MFMA: st = MFMA(K-frag, Q-frag) gives S^T in C-layout -> pk2 + b64
// writes to lP (XOR swizzle). Softmax fused per-mi (R13): only one mi's
// scores live -> VGPR back under the 102 / 5-waves-per-SIMD boundary.
// l = rowsum(P) via MFMA(P, ones): lacc[i][r] row matches O-store rows ->
// per-lane rcp, no shuffles. No min-waves hint (R11 spill lesson).
// ---------------------------------------------------------------------------
__global__ __launch_bounds__(256) void attn_kernel(
    const __hip_bfloat16* __restrict__ Q,
    const __hip_bfloat16* __restrict__ Kg,
    const __hip_bfloat16* __restrict__ Vt,
    __hip_bfloat16* __restrict__ O,
    int S, int BS)
{
    // g -> qt permutation: residency groups {x, x+4, x+8, x+12} each sum to
    // 30 kt-units -> per-CU balanced; heavy blocks first. bh stays bid&63 so
    // all qt-blocks of one (b,h) keep sharing an XCD (K/V L2-local).
    const int g = blockIdx.x >> 6;        // 0..15 (S=2048)
    const int qt = (g < 4) ? 15 - g : (g < 8) ? 11 - g : (g < 12) ? g : g - 12;
    const int bh = blockIdx.x & 63;
    const int b = bh >> 4, h = bh & 15;
    const int tid = threadIdx.x;
    const int wave = tid >> 6, lane = tid & 63;
    const int m16 = lane & 15, quad = lane >> 4;

    __shared__ __hip_bfloat16 lK[64 * 64];
    __shared__ __hip_bfloat16 lV[64 * 64];        // Vt tile: [d][kv]
    __shared__ __hip_bfloat16 lP[4][32 * 64];     // total LDS = 32768 B

    const int qrow0 = qt * 128 + wave * 32;
    const int64_t rowbase = (int64_t)b * S;

    // Q frags (B-operand of the S^T MFMA): aq[ni][ks]
    short8 aq[2][2];
#pragma unroll
    for (int i = 0; i < 2; i++) {
        const __hip_bfloat16* qp = Q + (rowbase + qrow0 + i * 16 + m16) * 1024 + h * 64 + quad * 8;
        aq[i][0] = *(const short8*)qp;
        aq[i][1] = *(const short8*)(qp + 32);
    }

    const short8 ones8 = {16256, 16256, 16256, 16256, 16256, 16256, 16256, 16256}; // bf16 1.0
    float4v lacc[2] = {};                         // rowsum(P) accumulator
    float4v o_acc[2][4] = {};

    const int srow = tid >> 3;
    const int scol = (tid & 7) * 8;

    const int ktmax_blk = 2 * qt + 1;
    const int ktmax_w = 2 * qt + (wave >> 1);
    const int k8 = (m16 & 7) * 8;                 // lP swizzle key (elems)

    short8 pk0, pk1, pv0, pv1;
#define PREFETCH(KT)                                                                          \
    do {                                                                                      \
        pk0 = *(const short8*)(Kg + (rowbase + (KT) * 64 + srow) * 1024 + h * 64 + scol);     \
        pk1 = *(const short8*)(Kg + (rowbase + (KT) * 64 + srow + 32) * 1024 + h * 64 + scol);\
        pv0 = *(const short8*)(Vt + (int64_t)(h * 64 + srow) * BS + rowbase + (KT) * 64 + scol);      \
        pv1 = *(const short8*)(Vt + (int64_t)(h * 64 + srow + 32) * BS + rowbase + (KT) * 64 + scol); \
    } while (0)

    PREFETCH(0);

    for (int kt = 0; kt <= ktmax_blk; kt++) {
        __syncthreads();
        *(short8*)&lK[srow * 64 + (scol ^ ((srow & 7) * 8))] = pk0;
        *(short8*)&lK[(srow + 32) * 64 + (scol ^ (((srow + 32) & 7) * 8))] = pk1;
        *(short8*)&lV[srow * 64 + (scol ^ ((srow & 7) * 8))] = pv0;
        *(short8*)&lV[(srow + 32) * 64 + (scol ^ (((srow + 32) & 7) * 8))] = pv1;
        __syncthreads();

        if (kt < ktmax_blk) PREFETCH(kt + 1);

        if (kt <= ktmax_w) {
            const bool need_mask = (kt * 64 + 63 > qrow0);

            // Per-mi: S^T MFMAs then immediately exp2/mask/pack/write.
            // Only one mi's scores (8 VGPRs) live at a time; compiler
            // overlaps mi+1's MFMAs with mi's softmax (no barriers).
#pragma unroll
            for (int mi = 0; mi < 4; mi++) {
                const int n = mi * 16 + m16;
                const int sw = (n & 7) * 8;
                const short8 k0 = *(const short8*)&lK[n * 64 + ((quad * 8) ^ sw)];
                const short8 k1 = *(const short8*)&lK[n * 64 + ((32 + quad * 8) ^ sw)];
                float4v s0 = {}, s1 = {};
                s0 = MFMA16(k0, aq[0][0], s0);
                s0 = MFMA16(k1, aq[0][1], s0);
                s1 = MFMA16(k0, aq[1][0], s1);
                s1 = MFMA16(k1, aq[1][1], s1);
#pragma unroll
                for (int ni = 0; ni < 2; ni++) {
                    const float4v sv = ni ? s1 : s0;
                    const int qg = qrow0 + ni * 16 + m16;
                    float p[4];
#pragma unroll
                    for (int r = 0; r < 4; r++) {
                        p[r] = exp2f(sv[r]);
                        if (need_mask) {
                            const int kvg = kt * 64 + mi * 16 + quad * 4 + r;
                            if (kvg > qg) p[r] = 0.0f;
                        }
                    }
                    uint2 w;
                    w.x = pk2(p[0], p[1]);
                    w.y = pk2(p[2], p[3]);
                    *(uint2*)&lP[wave][(ni * 16 + m16) * 64 + ((mi * 16 + quad * 4) ^ k8)] = w;
                }
            }

            // O += P V, l += P 1 (lP wave-private; lgkmcnt ordering suffices)
            short8 ap[2][2];
#pragma unroll
            for (int i = 0; i < 2; i++)
#pragma unroll
                for (int ks = 0; ks < 2; ks++)
                    ap[i][ks] = *(const short8*)
                        &lP[wave][(i * 16 + m16) * 64 + ((ks * 32 + quad * 8) ^ k8)];
#pragma unroll
            for (int i = 0; i < 2; i++) {
                lacc[i] = MFMA16(ap[i][0], ones8, lacc[i]);
                lacc[i] = MFMA16(ap[i][1], ones8, lacc[i]);
            }
#pragma unroll
            for (int jd = 0; jd < 4; jd++) {
                const int d = jd * 16 + m16;
                const int sw = (d & 7) * 8;
                short8 b0 = *(const short8*)&lV[d * 64 + ((quad * 8) ^ sw)];
                short8 b1 = *(const short8*)&lV[d * 64 + ((32 + quad * 8) ^ sw)];
#pragma unroll
                for (int i = 0; i < 2; i++) {
                    o_acc[i][jd] = MFMA16(ap[i][0], b0, o_acc[i][jd]);
                    o_acc[i][jd] = MFMA16(ap[i][1], b1, o_acc[i][jd]);
                }
            }
        }
    }
#undef PREFETCH

    // lacc C-layout: lacc[i][r] holds rowsum for row = i*16 + quad*4 + r —
    // exactly the O-store rows. Per-lane reciprocal, no shuffles.
    float ri[2][4];
#pragma unroll
    for (int i = 0; i < 2; i++)
#pragma unroll
        for (int r = 0; r < 4; r++)
            ri[i][r] = 1.0f / lacc[i][r];

#pragma unroll
    for (int i = 0; i < 2; i++)
#pragma unroll
        for (int jd = 0; jd < 4; jd++)
#pragma unroll
            for (int r = 0; r < 4; r++) {
                const int row = qrow0 + i * 16 + quad * 4 + r;
                O[(rowbase + row) * 1024 + h * 64 + jd * 16 + m16] =
                    __float2bfloat16(o_acc[i][jd][r] * ri[i][r]);
            }
}

// ---------------------------------------------------------------------------
extern "C" void kernel_launch(void* const* d_in, const int* in_sizes, int n_in,
                              void* d_out, int out_size, void* d_ws, size_t ws_size,
                              hipStream_t stream)
{
    const float* x  = (const float*)d_in[0];
    const float* qw = (const float*)d_in[1];
    const float* kw = (const float*)d_in[2];
    const float* vw = (const float*)d_in[3];
    const float* ow = (const float*)d_in[4];

    const int BS = 8192, D = 1024, S = 2048;
    const size_t MiB = 1024 * 1024;

    char* ws = (char*)d_ws;
    __hip_bfloat16* xb  = (__hip_bfloat16*)(ws);            // dead after qkv
    __hip_bfloat16* Qb  = (__hip_bfloat16*)(ws + 16 * MiB); // also AO
    __hip_bfloat16* Kb  = (__hip_bfloat16*)(ws + 32 * MiB);
    __hip_bfloat16* Vtb = (__hip_bfloat16*)(ws + 48 * MiB);
    __hip_bfloat16* wqb = (__hip_bfloat16*)(ws + 64 * MiB);
    __hip_bfloat16* wkb = (__hip_bfloat16*)(ws + 66 * MiB);
    __hip_bfloat16* wvb = (__hip_bfloat16*)(ws + 68 * MiB);
    __hip_bfloat16* wob = (__hip_bfloat16*)(ws + 70 * MiB);
    float2* table = (float2*)(ws);                          // overlays dead xb
    const bool wbf = ws_size >= 72 * MiB;                   // fast path fits?

    dim3 blk(256);
    convert_kernel<<<(BS * D) / 2048, blk, 0, stream>>>(x, xb);
    if (wbf) {
        convert4_kernel<<<4 * (D * D) / 2048, blk, 0, stream>>>(
            qw, kw, vw, ow, wqb, wkb, wvb, wob);
        qkv_gemm<1><<<64 * 24, blk, 0, stream>>>(xb, wqb, wkb, wvb, Qb, Kb, Vtb);
    } else {
        qkv_gemm<0><<<64 * 24, blk, 0, stream>>>(xb, qw, kw, vw, Qb, Kb, Vtb);
    }
    rope_table_kernel<<<256, blk, 0, stream>>>(table);      // after qkv: xb dead
    rope2_kernel<<<2 * 16384, blk, 0, stream>>>(Qb, Kb, table);
    attn_kernel<<<4 * 16 * (S / 128), blk, 0, stream>>>(Qb, Kb, Vtb, Qb /*AO*/, S, BS);
    if (wbf) gemm_o<1><<<(BS / 128) * (D / 64), blk, 0, stream>>>(Qb, wob, (float*)d_out, BS, D, D);
    else     gemm_o<0><<<(BS / 128) * (D / 64), blk, 0, stream>>>(Qb, ow,  (float*)d_out, BS, D, D);
}

// Round 6
// 287.856 us; speedup vs baseline: 1.1143x; 1.1143x over previous
//
#include <hip/hip_runtime.h>
#include <hip/hip_bf16.h>
#include <cstdint>

// B=4, S=2048, D=1024, NH=16, DK=64. Inputs fp32, output fp32.
// Pipeline:
//   convert: xb = bf16(x); weights -> bf16 in ONE launch (fast path)
//   qkv_gemm (fused, 1536 blocks): Q|K plain bf16 stores; V -> LDS-transpose
//            (XOR-swizzled, stride 128 -> LDS exactly 32 KiB) -> Vt[1024][8192].
//   rope_table -> rope2 (Q scale=log2e/8 and K in one launch)
//   attn: causal flash, fixed-max exp2 softmax, S^T-MFMA (R10-proven form:
//         VALU lsum + shfl epilogue; VGPR 80 -> 5 blocks/CU).
//   gemm_o: 128x64 tiles (1024 blocks), out = AO @ o_proj^T -> fp32
//
// R13 post-mortem: lacc-MFMA rowsum costs +24 VGPR (80->104) regardless of
// softmax fusion shape (R12 bulk = R13 per-mi = 104) -> crosses the 102
// (512/5) boundary -> 4 blocks/CU, attn 108-115us vs R10's 81.5. The VALU
// saving (~48 cyc/kt) never pays for a 20% occupancy loss.
// R14: attn reverted to R10-exact (VALU lsum[2], shfl-xor reduce, shfl
// 1/l redistribution). Keep: qkv 32KiB swizzle epilogue, gemm_o BN=64,
// convert4 fusion, rope2 fusion. Lessons: R11 = don't cap regs below
// natural; R13 = check occupancy-cliff cost before moving work across pipes.

typedef __attribute__((ext_vector_type(8))) short short8;
typedef __attribute__((ext_vector_type(4))) float float4v;

#define MFMA16(a, b, c) __builtin_amdgcn_mfma_f32_16x16x32_bf16((a), (b), (c), 0, 0, 0)

__device__ __forceinline__ void glds16(const void* g, void* l) {
    __builtin_amdgcn_global_load_lds(
        (const __attribute__((address_space(1))) void*)g,
        (__attribute__((address_space(3))) void*)l, 16, 0, 0);
}

__device__ __forceinline__ unsigned int pk2(float a, float b) {
    __hip_bfloat162 h = __float22bfloat162_rn(make_float2(a, b));  // v_cvt_pk_bf16_f32
    union { __hip_bfloat162 h; unsigned int u; } v; v.h = h;
    return v.u;
}

__device__ __forceinline__ unsigned short f2bf(float x) {
    union { float f; unsigned int u; } v; v.f = x;
    unsigned int r = (v.u + 0x7FFFu + ((v.u >> 16) & 1u)) >> 16;   // RNE
    return (unsigned short)r;
}

__device__ __forceinline__ float bf2f(unsigned short b) {
    union { unsigned int u; float f; } v; v.u = ((unsigned int)b) << 16;
    return v.f;
}

// 8 contiguous fp32 -> bf16 bits (packed converts)
__device__ __forceinline__ short8 load8f(const float* p) {
    const float4 f0 = *(const float4*)p;
    const float4 f1 = *(const float4*)(p + 4);
    union { short8 s; unsigned int u[4]; } r;
    r.u[0] = pk2(f0.x, f0.y);
    r.u[1] = pk2(f0.z, f0.w);
    r.u[2] = pk2(f1.x, f1.y);
    r.u[3] = pk2(f1.z, f1.w);
    return r.s;
}

// ---------------------------------------------------------------------------
__global__ __launch_bounds__(256) void convert_kernel(
    const float* __restrict__ in, __hip_bfloat16* __restrict__ out)
{
    const int idx = (blockIdx.x * 256 + threadIdx.x) * 8;
    *(short8*)(out + idx) = load8f(in + idx);
}

// 4 weight matrices (1M elems each) in one launch: 512 blocks per matrix.
__global__ __launch_bounds__(256) void convert4_kernel(
    const float* __restrict__ a, const float* __restrict__ b,
    const float* __restrict__ c, const float* __restrict__ d,
    __hip_bfloat16* __restrict__ oa, __hip_bfloat16* __restrict__ ob,
    __hip_bfloat16* __restrict__ oc, __hip_bfloat16* __restrict__ od)
{
    const int m = blockIdx.x >> 9;
    const float* in = (m == 0) ? a : (m == 1) ? b : (m == 2) ? c : d;
    __hip_bfloat16* out = (m == 0) ? oa : (m == 1) ? ob : (m == 2) ? oc : od;
    const int idx = ((blockIdx.x & 511) * 256 + threadIdx.x) * 8;
    *(short8*)(out + idx) = load8f(in + idx);
}

// ---------------------------------------------------------------------------
__global__ __launch_bounds__(256) void rope_table_kernel(float2* __restrict__ table)
{
    const int idx = blockIdx.x * 256 + threadIdx.x;   // 65536
    const int pos = idx >> 5, fi = idx & 31;
    const float f = exp2f(-(float)fi * (13.287712379549449f / 32.0f));
    float sn, cs;
    sincosf((float)pos * f, &sn, &cs);
    table[idx] = make_float2(cs, sn);
}

// ---------------------------------------------------------------------------
// Rope in place on Q and K [8192][1024] in one launch; pairs (2i,2i+1) per
// 64-dim head, pos=row%2048. Q half gets scale=log2e/8, K half 1.0.
// ---------------------------------------------------------------------------
__global__ __launch_bounds__(256) void rope2_kernel(
    __hip_bfloat16* __restrict__ Qp, __hip_bfloat16* __restrict__ Kp,
    const float2* __restrict__ table)
{
    const int sel = blockIdx.x >> 14;                 // 0 = Q, 1 = K
    __hip_bfloat16* T = sel ? Kp : Qp;
    const float scale = sel ? 1.0f : 0.18033688011112042f;
    const int idx = (blockIdx.x & 16383) * 256 + threadIdx.x;   // 8192*512
    const int r = idx >> 9;
    const int p = idx & 511;
    const int h = p >> 5, i = p & 31;
    const float2 cs = table[(r & 2047) * 32 + i];
    unsigned short* ptr = (unsigned short*)T + (int64_t)r * 1024 + h * 64 + 2 * i;
    const ushort2 xv = *(const ushort2*)ptr;
    const float x1 = bf2f(xv.x), x2 = bf2f(xv.y);
    const unsigned int o = pk2((x1 * cs.x - x2 * cs.y) * scale,
                               (x1 * cs.y + x2 * cs.x) * scale);
    *(unsigned int*)ptr = o;
}

// ---------------------------------------------------------------------------
// Fused QKV GEMM. A = xb [8192x1024] bf16 (glds16). B = {wq,wk,wv}[1024x1024]:
// BBF=1 -> bf16 glds16; BBF=0 -> fp32 packed register-convert.
// Q/K: plain bf16 store. V: XOR-swizzled LDS-transpose -> Vt coalesced.
// LDS = 128*128 halves = 32768 B. No min-waves hint (R11 lesson).
// ---------------------------------------------------------------------------
template<int BBF>
__global__ __launch_bounds__(256) void qkv_gemm(
    const __hip_bfloat16* __restrict__ Abf,
    const void* __restrict__ Wq, const void* __restrict__ Wk, const void* __restrict__ Wv,
    __hip_bfloat16* __restrict__ Qp, __hip_bfloat16* __restrict__ Kp,
    __hip_bfloat16* __restrict__ Vt)
{
    __shared__ unsigned short smem[128 * 128];   // 32768 B; staging uses [0..8191]

    const int K = 1024;
    const int bm = blockIdx.x / 24, bn = blockIdx.x % 24;
    const int widx = bn >> 3;              // 0=Q 1=K 2=V
    const int bcol0 = (bn & 7) * 128;
    const void* W = (widx == 0) ? Wq : (widx == 1) ? Wk : Wv;

    const int tid = threadIdx.x;
    const int wave = tid >> 6, lane = tid & 63;
    const int wm = (wave >> 1) * 64, wn = (wave & 1) * 64;
    const int m16 = lane & 15, quad = lane >> 4;

    const int lrow = lane >> 2, lcol = (lane & 3) * 8;   // glds map
    const int srow = tid >> 2, scol = (tid & 3) * 8;     // register-path map

    float4v acc[4][4] = {};

    for (int k0 = 0; k0 < K; k0 += 32) {
        short8 rb0, rb1;
        if (!BBF) {
            const float* Wf = (const float*)W;
            rb0 = load8f(Wf + (int64_t)(bcol0 + srow) * K + scol + k0);
            rb1 = load8f(Wf + (int64_t)(bcol0 + 64 + srow) * K + scol + k0);
        }
        __syncthreads();
        {
            const __hip_bfloat16* g = Abf + (int64_t)(bm * 128 + wave * 32 + lrow) * K + lcol + k0;
            glds16(g, &smem[wave * 1024]);
            glds16(g + (int64_t)16 * K, &smem[wave * 1024 + 512]);
        }
        if (BBF) {
            const __hip_bfloat16* g = (const __hip_bfloat16*)W +
                (int64_t)(bcol0 + wave * 32 + lrow) * K + lcol + k0;
            glds16(g, &smem[4096 + wave * 1024]);
            glds16(g + (int64_t)16 * K, &smem[4096 + wave * 1024 + 512]);
        } else {
            *(short8*)&smem[4096 + srow * 32 + scol] = rb0;
            *(short8*)&smem[4096 + (64 + srow) * 32 + scol] = rb1;
        }
        __syncthreads();

        short8 af[4], bf[4];
#pragma unroll
        for (int i = 0; i < 4; i++)
            af[i] = *(const short8*)&smem[(wm + i * 16 + m16) * 32 + quad * 8];
#pragma unroll
        for (int j = 0; j < 4; j++)
            bf[j] = *(const short8*)&smem[4096 + (wn + j * 16 + m16) * 32 + quad * 8];
#pragma unroll
        for (int i = 0; i < 4; i++)
#pragma unroll
            for (int j = 0; j < 4; j++)
                acc[i][j] = MFMA16(af[i], bf[j], acc[i][j]);
    }

    if (widx == 2) {
        // ---- V: transpose through LDS (XOR swizzle, stride 128) ----
        __syncthreads();
#pragma unroll
        for (int i = 0; i < 4; i++)
#pragma unroll
            for (int j = 0; j < 4; j++) {
                const int col = wn + j * 16 + m16;
                const int key = (col & 7) * 8;
#pragma unroll
                for (int r = 0; r < 4; r++) {
                    const int row = wm + i * 16 + quad * 4 + r;
                    smem[col * 128 + (row ^ key)] = f2bf(acc[i][j][r]);
                }
            }
        __syncthreads();
        const int dc = tid >> 4;          // 0..15
        const int seg = (tid & 15) * 8;   // 0..120 (mult of 8 -> XOR stays contiguous)
#pragma unroll
        for (int pass = 0; pass < 8; pass++) {
            const int dcol = pass * 16 + dc;
            const short8 v = *(const short8*)&smem[dcol * 128 + (seg ^ ((dcol & 7) * 8))];
            *(short8*)((unsigned short*)Vt + (int64_t)(bcol0 + dcol) * 8192 + bm * 128 + seg) = v;
        }
    } else {
        // ---- Q/K: plain store (C layout: col = lane&15, row = quad*4+r) ----
        __hip_bfloat16* dst = (widx == 0) ? Qp : Kp;
        const int row0 = bm * 128 + wm + quad * 4;
        const int col0 = bcol0 + wn + m16;
#pragma unroll
        for (int i = 0; i < 4; i++)
#pragma unroll
            for (int j = 0; j < 4; j++)
#pragma unroll
                for (int r = 0; r < 4; r++)
                    dst[(int64_t)(row0 + i * 16 + r) * 1024 + col0 + j * 16] =
                        __float2bfloat16(acc[i][j][r]);
    }
}

// ---------------------------------------------------------------------------
// Output GEMM: C[8192][1024] fp32 = A(bf16, glds16) * B^T; BBF as above.
// BM=128, BN=64 -> 1024 blocks (4/CU resident) for latency hiding.
// ---------------------------------------------------------------------------
template<int BBF>
__global__ __launch_bounds__(256) void gemm_o(
    const __hip_bfloat16* __restrict__ Abf, const void* __restrict__ B,
    float* __restrict__ C, int M, int N, int K)
{
    __shared__ __hip_bfloat16 lA[128 * 32];
    __shared__ __hip_bfloat16 lB[64 * 32];

    const int nb = N >> 6;
    const int bm = blockIdx.x / nb, bn = blockIdx.x % nb;
    const int tid = threadIdx.x;
    const int wave = tid >> 6, lane = tid & 63;
    const int wm = (wave >> 1) * 64, wn = (wave & 1) * 32;
    const int m16 = lane & 15, quad = lane >> 4;
    const int lrow = lane >> 2, lcol = (lane & 3) * 8;
    const int srow = tid >> 2, scol = (tid & 3) * 8;

    float4v acc[4][2] = {};

    for (int k0 = 0; k0 < K; k0 += 32) {
        short8 rb0;
        if (!BBF) {
            const float* Bf = (const float*)B;
            rb0 = load8f(Bf + (int64_t)(bn * 64 + srow) * K + scol + k0);
        }
        __syncthreads();
        {
            const __hip_bfloat16* g = Abf + (int64_t)(bm * 128 + wave * 32 + lrow) * K + lcol + k0;
            glds16(g, &lA[wave * 1024]);
            glds16(g + (int64_t)16 * K, &lA[wave * 1024 + 512]);
        }
        if (BBF) {
            // 4 waves x 16 rows each: lane>>2 = row 0..15, (lane&3)*8 = col
            glds16((const __hip_bfloat16*)B +
                   (int64_t)(bn * 64 + wave * 16 + (lane >> 2)) * K + lcol + k0,
                   &lB[wave * 512]);
        } else {
            *(short8*)&lB[srow * 32 + scol] = rb0;
        }
        __syncthreads();

        short8 af[4], bf[2];
#pragma unroll
        for (int i = 0; i < 4; i++)
            af[i] = *(const short8*)&lA[(wm + i * 16 + m16) * 32 + quad * 8];
#pragma unroll
        for (int j = 0; j < 2; j++)
            bf[j] = *(const short8*)&lB[(wn + j * 16 + m16) * 32 + quad * 8];
#pragma unroll
        for (int i = 0; i < 4; i++)
#pragma unroll
            for (int j = 0; j < 2; j++)
                acc[i][j] = MFMA16(af[i], bf[j], acc[i][j]);
    }

    const int row0 = bm * 128 + wm + quad * 4;
    const int col0 = bn * 64 + wn + m16;
#pragma unroll
    for (int i = 0; i < 4; i++)
#pragma unroll
        for (int j = 0; j < 2; j++)
#pragma unroll
            for (int r = 0; r < 4; r++)
                C[(int64_t)(row0 + i * 16 + r) * N + col0 + j * 16] = acc[i][j][r];
}

// ---------------------------------------------------------------------------
// Flash attention, causal, fixed-max softmax (Q pre-scaled by log2e/8;
// p = exp2(score)). Block = 4 waves x 32 Q rows = 128; Bc = 64.
// S^T-MFMA: st[mi][ni] = MFMA(K-frag, Q-frag) gives S^T in C-layout, so each
// register quad holds 4 consecutive kv at fixed qrow -> pk2 + ds_write_b64
// into lP (XOR swizzle key, r-invariant). PV reads lP with the proven
// 0-conflict b128 pattern. lsum VALU-accumulated per (ni, m16); epilogue:
// 2 shuffles + shfl-gather of 1/l. R10-proven form: VGPR 80, 5 blocks/CU.
// ---------------------------------------------------------------------------
__global__ __launch_bounds__(256) void attn_kernel(
    const __hip_bfloat16* __restrict__ Q,
    const __hip_bfloat16* __restrict__ Kg,
    const __hip_bfloat16* __restrict__ Vt,
    __hip_bfloat16* __restrict__ O,
    int S, int BS)
{
    // g -> qt permutation: residency groups {x, x+4, x+8, x+12} each sum to
    // 30 kt-units -> per-CU balanced; heavy blocks first. bh stays bid&63 so
    // all qt-blocks of one (b,h) keep sharing an XCD (K/V L2-local).
    const int g = blockIdx.x >> 6;        // 0..15 (S=2048)
    const int qt = (g < 4) ? 15 - g : (g < 8) ? 11 - g : (g < 12) ? g : g - 12;
    const int bh = blockIdx.x & 63;
    const int b = bh >> 4, h = bh & 15;
    const int tid = threadIdx.x;
    const int wave = tid >> 6, lane = tid & 63;
    const int m16 = lane & 15, quad = lane >> 4;

    __shared__ __hip_bfloat16 lK[64 * 64];
    __shared__ __hip_bfloat16 lV[64 * 64];        // Vt tile: [d][kv]
    __shared__ __hip_bfloat16 lP[4][32 * 64];     // total LDS = 32768 B

    const int qrow0 = qt * 128 + wave * 32;
    const int64_t rowbase = (int64_t)b * S;

    // Q frags (B-operand of the S^T MFMA): aq[ni][ks]
    short8 aq[2][2];
#pragma unroll
    for (int i = 0; i < 2; i++) {
        const __hip_bfloat16* qp = Q + (rowbase + qrow0 + i * 16 + m16) * 1024 + h * 64 + quad * 8;
        aq[i][0] = *(const short8*)qp;
        aq[i][1] = *(const short8*)(qp + 32);
    }

    float lsum[2] = {0.f, 0.f};                   // per (ni, lane m16) partials
    float4v o_acc[2][4] = {};

    const int srow = tid >> 3;
    const int scol = (tid & 7) * 8;

    const int ktmax_blk = 2 * qt + 1;
    const int ktmax_w = 2 * qt + (wave >> 1);
    const int k8 = (m16 & 7) * 8;                 // lP swizzle key (elems)

    short8 pk0, pk1, pv0, pv1;
#define PREFETCH(KT)                                                                          \
    do {                                                                                      \
        pk0 = *(const short8*)(Kg + (rowbase + (KT) * 64 + srow) * 1024 + h * 64 + scol);     \
        pk1 = *(const short8*)(Kg + (rowbase + (KT) * 64 + srow + 32) * 1024 + h * 64 + scol);\
        pv0 = *(const short8*)(Vt + (int64_t)(h * 64 + srow) * BS + rowbase + (KT) * 64 + scol);      \
        pv1 = *(const short8*)(Vt + (int64_t)(h * 64 + srow + 32) * BS + rowbase + (KT) * 64 + scol); \
    } while (0)

    PREFETCH(0);

    for (int kt = 0; kt <= ktmax_blk; kt++) {
        __syncthreads();
        *(short8*)&lK[srow * 64 + (scol ^ ((srow & 7) * 8))] = pk0;
        *(short8*)&lK[(srow + 32) * 64 + (scol ^ (((srow + 32) & 7) * 8))] = pk1;
        *(short8*)&lV[srow * 64 + (scol ^ ((srow & 7) * 8))] = pv0;
        *(short8*)&lV[(srow + 32) * 64 + (scol ^ (((srow + 32) & 7) * 8))] = pv1;
        __syncthreads();

        if (kt < ktmax_blk) PREFETCH(kt + 1);

        if (kt <= ktmax_w) {
            // S^T = K Q^T : st[mi][ni], C-layout row = kv, col = qrow
            float4v st[4][2] = {};
#pragma unroll
            for (int mi = 0; mi < 4; mi++) {
                const int n = mi * 16 + m16;
                const int sw = (n & 7) * 8;
                short8 k0 = *(const short8*)&lK[n * 64 + ((quad * 8) ^ sw)];
                short8 k1 = *(const short8*)&lK[n * 64 + ((32 + quad * 8) ^ sw)];
#pragma unroll
                for (int ni = 0; ni < 2; ni++) {
                    st[mi][ni] = MFMA16(k0, aq[ni][0], st[mi][ni]);
                    st[mi][ni] = MFMA16(k1, aq[ni][1], st[mi][ni]);
                }
            }

            // exp2, causal mask, lsum partials, packed b64 write to lP
            const bool need_mask = (kt * 64 + 63 > qrow0);
#pragma unroll
            for (int ni = 0; ni < 2; ni++) {
                const int qg = qrow0 + ni * 16 + m16;
#pragma unroll
                for (int mi = 0; mi < 4; mi++) {
                    float p[4];
#pragma unroll
                    for (int r = 0; r < 4; r++) {
                        p[r] = exp2f(st[mi][ni][r]);
                        if (need_mask) {
                            const int kvg = kt * 64 + mi * 16 + quad * 4 + r;
                            if (kvg > qg) p[r] = 0.0f;
                        }
                    }
                    lsum[ni] += (p[0] + p[1]) + (p[2] + p[3]);
                    uint2 w;
                    w.x = pk2(p[0], p[1]);
                    w.y = pk2(p[2], p[3]);
                    *(uint2*)&lP[wave][(ni * 16 + m16) * 64 + ((mi * 16 + quad * 4) ^ k8)] = w;
                }
            }

            // O += P V (lP wave-private; lgkmcnt ordering suffices)
            short8 ap[2][2];
#pragma unroll
            for (int i = 0; i < 2; i++)
#pragma unroll
                for (int ks = 0; ks < 2; ks++)
                    ap[i][ks] = *(const short8*)
                        &lP[wave][(i * 16 + m16) * 64 + ((ks * 32 + quad * 8) ^ k8)];
#pragma unroll
            for (int jd = 0; jd < 4; jd++) {
                const int d = jd * 16 + m16;
                const int sw = (d & 7) * 8;
                short8 b0 = *(const short8*)&lV[d * 64 + ((quad * 8) ^ sw)];
                short8 b1 = *(const short8*)&lV[d * 64 + ((32 + quad * 8) ^ sw)];
#pragma unroll
                for (int i = 0; i < 2; i++) {
                    o_acc[i][jd] = MFMA16(ap[i][0], b0, o_acc[i][jd]);
                    o_acc[i][jd] = MFMA16(ap[i][1], b1, o_acc[i][jd]);
                }
            }
        }
    }
#undef PREFETCH

    // l reduction: after xor16+xor32 every lane holds its m16-column's full
    // sum; invert once, then shfl-gather 1/l for the O-store lanes (no LDS).
    float rinv[2];
#pragma unroll
    for (int ni = 0; ni < 2; ni++) {
        float v = lsum[ni];
        v += __shfl_xor(v, 16);
        v += __shfl_xor(v, 32);
        rinv[ni] = 1.0f / v;
    }
    float ri[2][4];
#pragma unroll
    for (int i = 0; i < 2; i++)
#pragma unroll
        for (int r = 0; r < 4; r++)
            ri[i][r] = __shfl(rinv[i], quad * 4 + r);   // lane p holds column p

#pragma unroll
    for (int i = 0; i < 2; i++)
#pragma unroll
        for (int jd = 0; jd < 4; jd++)
#pragma unroll
            for (int r = 0; r < 4; r++) {
                const int row = qrow0 + i * 16 + quad * 4 + r;
                O[(rowbase + row) * 1024 + h * 64 + jd * 16 + m16] =
                    __float2bfloat16(o_acc[i][jd][r] * ri[i][r]);
            }
}

// ---------------------------------------------------------------------------
extern "C" void kernel_launch(void* const* d_in, const int* in_sizes, int n_in,
                              void* d_out, int out_size, void* d_ws, size_t ws_size,
                              hipStream_t stream)
{
    const float* x  = (const float*)d_in[0];
    const float* qw = (const float*)d_in[1];
    const float* kw = (const float*)d_in[2];
    const float* vw = (const float*)d_in[3];
    const float* ow = (const float*)d_in[4];

    const int BS = 8192, D = 1024, S = 2048;
    const size_t MiB = 1024 * 1024;

    char* ws = (char*)d_ws;
    __hip_bfloat16* xb  = (__hip_bfloat16*)(ws);            // dead after qkv
    __hip_bfloat16* Qb  = (__hip_bfloat16*)(ws + 16 * MiB); // also AO
    __hip_bfloat16* Kb  = (__hip_bfloat16*)(ws + 32 * MiB);
    __hip_bfloat16* Vtb = (__hip_bfloat16*)(ws + 48 * MiB);
    __hip_bfloat16* wqb = (__hip_bfloat16*)(ws + 64 * MiB);
    __hip_bfloat16* wkb = (__hip_bfloat16*)(ws + 66 * MiB);
    __hip_bfloat16* wvb = (__hip_bfloat16*)(ws + 68 * MiB);
    __hip_bfloat16* wob = (__hip_bfloat16*)(ws + 70 * MiB);
    float2* table = (float2*)(ws);                          // overlays dead xb
    const bool wbf = ws_size >= 72 * MiB;                   // fast path fits?

    dim3 blk(256);
    convert_kernel<<<(BS * D) / 2048, blk, 0, stream>>>(x, xb);
    if (wbf) {
        convert4_kernel<<<4 * (D * D) / 2048, blk, 0, stream>>>(
            qw, kw, vw, ow, wqb, wkb, wvb, wob);
        qkv_gemm<1><<<64 * 24, blk, 0, stream>>>(xb, wqb, wkb, wvb, Qb, Kb, Vtb);
    } else {
        qkv_gemm<0><<<64 * 24, blk, 0, stream>>>(xb, qw, kw, vw, Qb, Kb, Vtb);
    }
    rope_table_kernel<<<256, blk, 0, stream>>>(table);      // after qkv: xb dead
    rope2_kernel<<<2 * 16384, blk, 0, stream>>>(Qb, Kb, table);
    attn_kernel<<<4 * 16 * (S / 128), blk, 0, stream>>>(Qb, Kb, Vtb, Qb /*AO*/, S, BS);
    if (wbf) gemm_o<1><<<(BS / 128) * (D / 64), blk, 0, stream>>>(Qb, wob, (float*)d_out, BS, D, D);
    else     gemm_o<0><<<(BS / 128) * (D / 64), blk, 0, stream>>>(Qb, ow,  (float*)d_out, BS, D, D);
}

// Round 7
// 265.406 us; speedup vs baseline: 1.2085x; 1.0846x over previous
//
#include <hip/hip_runtime.h>
#include <hip/hip_bf16.h>
#include <cstdint>

// B=4, S=2048, D=1024, NH=16, DK=64. Inputs fp32, output fp32.
// Pipeline:
//   convert: xb = bf16(x); weights -> bf16 in ONE launch (fast path)
//   qkv_gemm (fused, 1536 blocks): BK=64, XOR-swizzled staging (conflict-free
//            ds_read_b128); Q|K plain stores; V -> LDS-transpose -> Vt.
//   rope_table -> rope2 (Q scale=log2e/8 and K in one launch)
//   attn: causal flash, fixed-max exp2 softmax, S^T-MFMA (R10-proven form:
//         VALU lsum + shfl epilogue; VGPR 80 -> 5 blocks/CU). UNTOUCHED.
//   gemm_o: BK=64, swizzled staging, 128x64 tiles (1024 blocks) -> fp32 out.
//
// R14 post-mortem: qkv now #1 (84.4us): BANK_CONFLICT 6.55M, MfmaUtil 26%.
// The [128][32] staging tile (64B row stride) makes every b128 fragment
// read an 8-way bank conflict (start bank = m16*16+quad*4 mod 32 -> 8
// lanes/span). Also BK=32 = only 16 MFMA per barrier-pair, 32 pairs.
// R15: (a) BK=64 (16 pairs, 32 MFMA/pair; qkv LDS A16K+B16K=32K, V-epilogue
// reuses); (b) XOR swizzle c^((r&7)*8) in 8-half granules, applied via
// PRE-SWIZZLED global source col ((l&7)^(l>>3))*8 (glds16 writes linearly;
// both-sides-or-neither) and XOR'd read offset -> span index
// (kk*4+quad)^(r&7): 8 spans uniform, 2 lanes/span = free. Same for gemm_o.
// attn untouched (VALU-bound, proven). No XCD swizzle (inputs L3-fit).

typedef __attribute__((ext_vector_type(8))) short short8;
typedef __attribute__((ext_vector_type(4))) float float4v;

#define MFMA16(a, b, c) __builtin_amdgcn_mfma_f32_16x16x32_bf16((a), (b), (c), 0, 0, 0)

__device__ __forceinline__ void glds16(const void* g, void* l) {
    __builtin_amdgcn_global_load_lds(
        (const __attribute__((address_space(1))) void*)g,
        (__attribute__((address_space(3))) void*)l, 16, 0, 0);
}

__device__ __forceinline__ unsigned int pk2(float a, float b) {
    __hip_bfloat162 h = __float22bfloat162_rn(make_float2(a, b));  // v_cvt_pk_bf16_f32
    union { __hip_bfloat162 h; unsigned int u; } v; v.h = h;
    return v.u;
}

__device__ __forceinline__ unsigned short f2bf(float x) {
    union { float f; unsigned int u; } v; v.f = x;
    unsigned int r = (v.u + 0x7FFFu + ((v.u >> 16) & 1u)) >> 16;   // RNE
    return (unsigned short)r;
}

__device__ __forceinline__ float bf2f(unsigned short b) {
    union { unsigned int u; float f; } v; v.u = ((unsigned int)b) << 16;
    return v.f;
}

// 8 contiguous fp32 -> bf16 bits (packed converts)
__device__ __forceinline__ short8 load8f(const float* p) {
    const float4 f0 = *(const float4*)p;
    const float4 f1 = *(const float4*)(p + 4);
    union { short8 s; unsigned int u[4]; } r;
    r.u[0] = pk2(f0.x, f0.y);
    r.u[1] = pk2(f0.z, f0.w);
    r.u[2] = pk2(f1.x, f1.y);
    r.u[3] = pk2(f1.z, f1.w);
    return r.s;
}

// ---------------------------------------------------------------------------
__global__ __launch_bounds__(256) void convert_kernel(
    const float* __restrict__ in, __hip_bfloat16* __restrict__ out)
{
    const int idx = (blockIdx.x * 256 + threadIdx.x) * 8;
    *(short8*)(out + idx) = load8f(in + idx);
}

// 4 weight matrices (1M elems each) in one launch: 512 blocks per matrix.
__global__ __launch_bounds__(256) void convert4_kernel(
    const float* __restrict__ a, const float* __restrict__ b,
    const float* __restrict__ c, const float* __restrict__ d,
    __hip_bfloat16* __restrict__ oa, __hip_bfloat16* __restrict__ ob,
    __hip_bfloat16* __restrict__ oc, __hip_bfloat16* __restrict__ od)
{
    const int m = blockIdx.x >> 9;
    const float* in = (m == 0) ? a : (m == 1) ? b : (m == 2) ? c : d;
    __hip_bfloat16* out = (m == 0) ? oa : (m == 1) ? ob : (m == 2) ? oc : od;
    const int idx = ((blockIdx.x & 511) * 256 + threadIdx.x) * 8;
    *(short8*)(out + idx) = load8f(in + idx);
}

// ---------------------------------------------------------------------------
__global__ __launch_bounds__(256) void rope_table_kernel(float2* __restrict__ table)
{
    const int idx = blockIdx.x * 256 + threadIdx.x;   // 65536
    const int pos = idx >> 5, fi = idx & 31;
    const float f = exp2f(-(float)fi * (13.287712379549449f / 32.0f));
    float sn, cs;
    sincosf((float)pos * f, &sn, &cs);
    table[idx] = make_float2(cs, sn);
}

// ---------------------------------------------------------------------------
// Rope in place on Q and K [8192][1024] in one launch; pairs (2i,2i+1) per
// 64-dim head, pos=row%2048. Q half gets scale=log2e/8, K half 1.0.
// ---------------------------------------------------------------------------
__global__ __launch_bounds__(256) void rope2_kernel(
    __hip_bfloat16* __restrict__ Qp, __hip_bfloat16* __restrict__ Kp,
    const float2* __restrict__ table)
{
    const int sel = blockIdx.x >> 14;                 // 0 = Q, 1 = K
    __hip_bfloat16* T = sel ? Kp : Qp;
    const float scale = sel ? 1.0f : 0.18033688011112042f;
    const int idx = (blockIdx.x & 16383) * 256 + threadIdx.x;   // 8192*512
    const int r = idx >> 9;
    const int p = idx & 511;
    const int h = p >> 5, i = p & 31;
    const float2 cs = table[(r & 2047) * 32 + i];
    unsigned short* ptr = (unsigned short*)T + (int64_t)r * 1024 + h * 64 + 2 * i;
    const ushort2 xv = *(const ushort2*)ptr;
    const float x1 = bf2f(xv.x), x2 = bf2f(xv.y);
    const unsigned int o = pk2((x1 * cs.x - x2 * cs.y) * scale,
                               (x1 * cs.y + x2 * cs.x) * scale);
    *(unsigned int*)ptr = o;
}

// ---------------------------------------------------------------------------
// Fused QKV GEMM, BK=64. A = xb [8192x1024] bf16 (glds16, pre-swizzled
// source). B = {wq,wk,wv}: BBF=1 bf16 glds16; BBF=0 fp32 register-convert.
// Staging layout: row r's col c stored at r*64 + (c ^ ((r&7)*8)) halves
// (conflict-free b128 reads). Q/K: plain store. V: swizzled LDS-transpose.
// LDS = 32768 B (A[0..8191] | B[8192..16383] halves; V-epilogue reuses all).
// ---------------------------------------------------------------------------
template<int BBF>
__global__ __launch_bounds__(256) void qkv_gemm(
    const __hip_bfloat16* __restrict__ Abf,
    const void* __restrict__ Wq, const void* __restrict__ Wk, const void* __restrict__ Wv,
    __hip_bfloat16* __restrict__ Qp, __hip_bfloat16* __restrict__ Kp,
    __hip_bfloat16* __restrict__ Vt)
{
    __shared__ unsigned short smem[128 * 128];   // 32 KiB

    const int K = 1024;
    const int bm = blockIdx.x / 24, bn = blockIdx.x % 24;
    const int widx = bn >> 3;              // 0=Q 1=K 2=V
    const int bcol0 = (bn & 7) * 128;
    const void* W = (widx == 0) ? Wq : (widx == 1) ? Wk : Wv;

    const int tid = threadIdx.x;
    const int wave = tid >> 6, lane = tid & 63;
    const int wm = (wave >> 1) * 64, wn = (wave & 1) * 64;
    const int m16 = lane & 15, quad = lane >> 4;

    const int grow = lane >> 3;                              // glds16: 8 rows/instr
    const int gcolsw = ((lane & 7) ^ (lane >> 3)) * 8;       // pre-swizzled col
    const int srow = tid >> 2, scol = (tid & 3) * 8;         // fp32 register-path

    float4v acc[4][4] = {};

    for (int k0 = 0; k0 < K; k0 += 64) {
        short8 rb[4];
        if (!BBF) {
            const float* Wf = (const float*)W;
#pragma unroll
            for (int t = 0; t < 4; t++)      // t = (rowhalf<<1)|colhalf
                rb[t] = load8f(Wf + (int64_t)(bcol0 + (t >> 1) * 64 + srow) * K
                               + k0 + (t & 1) * 32 + scol);
        }
        __syncthreads();
        {
            const __hip_bfloat16* g = Abf + (int64_t)(bm * 128 + wave * 32 + grow) * K + k0 + gcolsw;
#pragma unroll
            for (int t = 0; t < 4; t++)
                glds16(g + (int64_t)(t * 8) * K, &smem[(wave * 32 + t * 8) * 64]);
        }
        if (BBF) {
            const __hip_bfloat16* g = (const __hip_bfloat16*)W +
                (int64_t)(bcol0 + wave * 32 + grow) * K + k0 + gcolsw;
#pragma unroll
            for (int t = 0; t < 4; t++)
                glds16(g + (int64_t)(t * 8) * K, &smem[8192 + (wave * 32 + t * 8) * 64]);
        } else {
#pragma unroll
            for (int t = 0; t < 4; t++) {
                const int r = (t >> 1) * 64 + srow;
                const int c = (t & 1) * 32 + scol;
                *(short8*)&smem[8192 + r * 64 + (c ^ ((r & 7) * 8))] = rb[t];
            }
        }
        __syncthreads();

#pragma unroll
        for (int kk = 0; kk < 2; kk++) {
            const int ksw = (kk * 32 + quad * 8) ^ ((m16 & 7) * 8);
            short8 af[4], bf[4];
#pragma unroll
            for (int i = 0; i < 4; i++)
                af[i] = *(const short8*)&smem[(wm + i * 16 + m16) * 64 + ksw];
#pragma unroll
            for (int j = 0; j < 4; j++)
                bf[j] = *(const short8*)&smem[8192 + (wn + j * 16 + m16) * 64 + ksw];
#pragma unroll
            for (int i = 0; i < 4; i++)
#pragma unroll
                for (int j = 0; j < 4; j++)
                    acc[i][j] = MFMA16(af[i], bf[j], acc[i][j]);
        }
    }

    if (widx == 2) {
        // ---- V: transpose through LDS (XOR swizzle, stride 128) ----
        __syncthreads();
#pragma unroll
        for (int i = 0; i < 4; i++)
#pragma unroll
            for (int j = 0; j < 4; j++) {
                const int col = wn + j * 16 + m16;
                const int key = (col & 7) * 8;
#pragma unroll
                for (int r = 0; r < 4; r++) {
                    const int row = wm + i * 16 + quad * 4 + r;
                    smem[col * 128 + (row ^ key)] = f2bf(acc[i][j][r]);
                }
            }
        __syncthreads();
        const int dc = tid >> 4;          // 0..15
        const int seg = (tid & 15) * 8;   // 0..120 (mult of 8 -> XOR stays contiguous)
#pragma unroll
        for (int pass = 0; pass < 8; pass++) {
            const int dcol = pass * 16 + dc;
            const short8 v = *(const short8*)&smem[dcol * 128 + (seg ^ ((dcol & 7) * 8))];
            *(short8*)((unsigned short*)Vt + (int64_t)(bcol0 + dcol) * 8192 + bm * 128 + seg) = v;
        }
    } else {
        // ---- Q/K: plain store (C layout: col = lane&15, row = quad*4+r) ----
        __hip_bfloat16* dst = (widx == 0) ? Qp : Kp;
        const int row0 = bm * 128 + wm + quad * 4;
        const int col0 = bcol0 + wn + m16;
#pragma unroll
        for (int i = 0; i < 4; i++)
#pragma unroll
            for (int j = 0; j < 4; j++)
#pragma unroll
                for (int r = 0; r < 4; r++)
                    dst[(int64_t)(row0 + i * 16 + r) * 1024 + col0 + j * 16] =
                        __float2bfloat16(acc[i][j][r]);
    }
}

// ---------------------------------------------------------------------------
// Output GEMM, BK=64: C[8192][1024] fp32 = A(bf16, glds16) * B^T.
// Same swizzled staging as qkv. BM=128, BN=64 -> 1024 blocks; LDS 24 KiB.
// ---------------------------------------------------------------------------
template<int BBF>
__global__ __launch_bounds__(256) void gemm_o(
    const __hip_bfloat16* __restrict__ Abf, const void* __restrict__ B,
    float* __restrict__ C, int M, int N, int K)
{
    __shared__ __hip_bfloat16 lA[128 * 64];   // 16 KiB
    __shared__ __hip_bfloat16 lB[64 * 64];    //  8 KiB

    const int nb = N >> 6;
    const int bm = blockIdx.x / nb, bn = blockIdx.x % nb;
    const int tid = threadIdx.x;
    const int wave = tid >> 6, lane = tid & 63;
    const int wm = (wave >> 1) * 64, wn = (wave & 1) * 32;
    const int m16 = lane & 15, quad = lane >> 4;
    const int grow = lane >> 3;
    const int gcolsw = ((lane & 7) ^ (lane >> 3)) * 8;
    const int srow = tid >> 3, scol = (tid & 7) * 8;     // fp32 path: 32 rows x 64 cols

    float4v acc[4][2] = {};

    for (int k0 = 0; k0 < K; k0 += 64) {
        short8 rb[2];
        if (!BBF) {
            const float* Bf = (const float*)B;
#pragma unroll
            for (int t = 0; t < 2; t++)
                rb[t] = load8f(Bf + (int64_t)(bn * 64 + t * 32 + srow) * K + k0 + scol);
        }
        __syncthreads();
        {
            const __hip_bfloat16* g = Abf + (int64_t)(bm * 128 + wave * 32 + grow) * K + k0 + gcolsw;
#pragma unroll
            for (int t = 0; t < 4; t++)
                glds16(g + (int64_t)(t * 8) * K, &lA[(wave * 32 + t * 8) * 64]);
        }
        if (BBF) {
            const __hip_bfloat16* g = (const __hip_bfloat16*)B +
                (int64_t)(bn * 64 + wave * 16 + grow) * K + k0 + gcolsw;
#pragma unroll
            for (int t = 0; t < 2; t++)
                glds16(g + (int64_t)(t * 8) * K, &lB[(wave * 16 + t * 8) * 64]);
        } else {
#pragma unroll
            for (int t = 0; t < 2; t++) {
                const int r = t * 32 + srow;
                *(short8*)&lB[r * 64 + (scol ^ ((r & 7) * 8))] = rb[t];
            }
        }
        __syncthreads();

#pragma unroll
        for (int kk = 0; kk < 2; kk++) {
            const int ksw = (kk * 32 + quad * 8) ^ ((m16 & 7) * 8);
            short8 af[4], bf[2];
#pragma unroll
            for (int i = 0; i < 4; i++)
                af[i] = *(const short8*)&lA[(wm + i * 16 + m16) * 64 + ksw];
#pragma unroll
            for (int j = 0; j < 2; j++)
                bf[j] = *(const short8*)&lB[(wn + j * 16 + m16) * 64 + ksw];
#pragma unroll
            for (int i = 0; i < 4; i++)
#pragma unroll
                for (int j = 0; j < 2; j++)
                    acc[i][j] = MFMA16(af[i], bf[j], acc[i][j]);
        }
    }

    const int row0 = bm * 128 + wm + quad * 4;
    const int col0 = bn * 64 + wn + m16;
#pragma unroll
    for (int i = 0; i < 4; i++)
#pragma unroll
        for (int j = 0; j < 2; j++)
#pragma unroll
            for (int r = 0; r < 4; r++)
                C[(int64_t)(row0 + i * 16 + r) * N + col0 + j * 16] = acc[i][j][r];
}

// ---------------------------------------------------------------------------
// Flash attention, causal, fixed-max softmax (Q pre-scaled by log2e/8;
// p = exp2(score)). Block = 4 waves x 32 Q rows = 128; Bc = 64.
// S^T-MFMA: st[mi][ni] = MFMA(K-frag, Q-frag) gives S^T in C-layout, so each
// register quad holds 4 consecutive kv at fixed qrow -> pk2 + ds_write_b64
// into lP (XOR swizzle key, r-invariant). PV reads lP with the proven
// 0-conflict b128 pattern. lsum VALU-accumulated per (ni, m16); epilogue:
// 2 shuffles + shfl-gather of 1/l. R10-proven form: VGPR 80, 5 blocks/CU.
// ---------------------------------------------------------------------------
__global__ __launch_bounds__(256) void attn_kernel(
    const __hip_bfloat16* __restrict__ Q,
    const __hip_bfloat16* __restrict__ Kg,
    const __hip_bfloat16* __restrict__ Vt,
    __hip_bfloat16* __restrict__ O,
    int S, int BS)
{
    // g -> qt permutation: residency groups {x, x+4, x+8, x+12} each sum to
    // 30 kt-units -> per-CU balanced; heavy blocks first. bh stays bid&63 so
    // all qt-blocks of one (b,h) keep sharing an XCD (K/V L2-local).
    const int g = blockIdx.x >> 6;        // 0..15 (S=2048)
    const int qt = (g < 4) ? 15 - g : (g < 8) ? 11 - g : (g < 12) ? g : g - 12;
    const int bh = blockIdx.x & 63;
    const int b = bh >> 4, h = bh & 15;
    const int tid = threadIdx.x;
    const int wave = tid >> 6, lane = tid & 63;
    const int m16 = lane & 15, quad = lane >> 4;

    __shared__ __hip_bfloat16 lK[64 * 64];
    __shared__ __hip_bfloat16 lV[64 * 64];        // Vt tile: [d][kv]
    __shared__ __hip_bfloat16 lP[4][32 * 64];     // total LDS = 32768 B

    const int qrow0 = qt * 128 + wave * 32;
    const int64_t rowbase = (int64_t)b * S;

    // Q frags (B-operand of the S^T MFMA): aq[ni][ks]
    short8 aq[2][2];
#pragma unroll
    for (int i = 0; i < 2; i++) {
        const __hip_bfloat16* qp = Q + (rowbase + qrow0 + i * 16 + m16) * 1024 + h * 64 + quad * 8;
        aq[i][0] = *(const short8*)qp;
        aq[i][1] = *(const short8*)(qp + 32);
    }

    float lsum[2] = {0.f, 0.f};                   // per (ni, lane m16) partials
    float4v o_acc[2][4] = {};

    const int srow = tid >> 3;
    const int scol = (tid & 7) * 8;

    const int ktmax_blk = 2 * qt + 1;
    const int ktmax_w = 2 * qt + (wave >> 1);
    const int k8 = (m16 & 7) * 8;                 // lP swizzle key (elems)

    short8 pk0, pk1, pv0, pv1;
#define PREFETCH(KT)                                                                          \
    do {                                                                                      \
        pk0 = *(const short8*)(Kg + (rowbase + (KT) * 64 + srow) * 1024 + h * 64 + scol);     \
        pk1 = *(const short8*)(Kg + (rowbase + (KT) * 64 + srow + 32) * 1024 + h * 64 + scol);\
        pv0 = *(const short8*)(Vt + (int64_t)(h * 64 + srow) * BS + rowbase + (KT) * 64 + scol);      \
        pv1 = *(const short8*)(Vt + (int64_t)(h * 64 + srow + 32) * BS + rowbase + (KT) * 64 + scol); \
    } while (0)

    PREFETCH(0);

    for (int kt = 0; kt <= ktmax_blk; kt++) {
        __syncthreads();
        *(short8*)&lK[srow * 64 + (scol ^ ((srow & 7) * 8))] = pk0;
        *(short8*)&lK[(srow + 32) * 64 + (scol ^ (((srow + 32) & 7) * 8))] = pk1;
        *(short8*)&lV[srow * 64 + (scol ^ ((srow & 7) * 8))] = pv0;
        *(short8*)&lV[(srow + 32) * 64 + (scol ^ (((srow + 32) & 7) * 8))] = pv1;
        __syncthreads();

        if (kt < ktmax_blk) PREFETCH(kt + 1);

        if (kt <= ktmax_w) {
            // S^T = K Q^T : st[mi][ni], C-layout row = kv, col = qrow
            float4v st[4][2] = {};
#pragma unroll
            for (int mi = 0; mi < 4; mi++) {
                const int n = mi * 16 + m16;
                const int sw = (n & 7) * 8;
                short8 k0 = *(const short8*)&lK[n * 64 + ((quad * 8) ^ sw)];
                short8 k1 = *(const short8*)&lK[n * 64 + ((32 + quad * 8) ^ sw)];
#pragma unroll
                for (int ni = 0; ni < 2; ni++) {
                    st[mi][ni] = MFMA16(k0, aq[ni][0], st[mi][ni]);
                    st[mi][ni] = MFMA16(k1, aq[ni][1], st[mi][ni]);
                }
            }

            // exp2, causal mask, lsum partials, packed b64 write to lP
            const bool need_mask = (kt * 64 + 63 > qrow0);
#pragma unroll
            for (int ni = 0; ni < 2; ni++) {
                const int qg = qrow0 + ni * 16 + m16;
#pragma unroll
                for (int mi = 0; mi < 4; mi++) {
                    float p[4];
#pragma unroll
                    for (int r = 0; r < 4; r++) {
                        p[r] = exp2f(st[mi][ni][r]);
                        if (need_mask) {
                            const int kvg = kt * 64 + mi * 16 + quad * 4 + r;
                            if (kvg > qg) p[r] = 0.0f;
                        }
                    }
                    lsum[ni] += (p[0] + p[1]) + (p[2] + p[3]);
                    uint2 w;
                    w.x = pk2(p[0], p[1]);
                    w.y = pk2(p[2], p[3]);
                    *(uint2*)&lP[wave][(ni * 16 + m16) * 64 + ((mi * 16 + quad * 4) ^ k8)] = w;
                }
            }

            // O += P V (lP wave-private; lgkmcnt ordering suffices)
            short8 ap[2][2];
#pragma unroll
            for (int i = 0; i < 2; i++)
#pragma unroll
                for (int ks = 0; ks < 2; ks++)
                    ap[i][ks] = *(const short8*)
                        &lP[wave][(i * 16 + m16) * 64 + ((ks * 32 + quad * 8) ^ k8)];
#pragma unroll
            for (int jd = 0; jd < 4; jd++) {
                const int d = jd * 16 + m16;
                const int sw = (d & 7) * 8;
                short8 b0 = *(const short8*)&lV[d * 64 + ((quad * 8) ^ sw)];
                short8 b1 = *(const short8*)&lV[d * 64 + ((32 + quad * 8) ^ sw)];
#pragma unroll
                for (int i = 0; i < 2; i++) {
                    o_acc[i][jd] = MFMA16(ap[i][0], b0, o_acc[i][jd]);
                    o_acc[i][jd] = MFMA16(ap[i][1], b1, o_acc[i][jd]);
                }
            }
        }
    }
#undef PREFETCH

    // l reduction: after xor16+xor32 every lane holds its m16-column's full
    // sum; invert once, then shfl-gather 1/l for the O-store lanes (no LDS).
    float rinv[2];
#pragma unroll
    for (int ni = 0; ni < 2; ni++) {
        float v = lsum[ni];
        v += __shfl_xor(v, 16);
        v += __shfl_xor(v, 32);
        rinv[ni] = 1.0f / v;
    }
    float ri[2][4];
#pragma unroll
    for (int i = 0; i < 2; i++)
#pragma unroll
        for (int r = 0; r < 4; r++)
            ri[i][r] = __shfl(rinv[i], quad * 4 + r);   // lane p holds column p

#pragma unroll
    for (int i = 0; i < 2; i++)
#pragma unroll
        for (int jd = 0; jd < 4; jd++)
#pragma unroll
            for (int r = 0; r < 4; r++) {
                const int row = qrow0 + i * 16 + quad * 4 + r;
                O[(rowbase + row) * 1024 + h * 64 + jd * 16 + m16] =
                    __float2bfloat16(o_acc[i][jd][r] * ri[i][r]);
            }
}

// ---------------------------------------------------------------------------
extern "C" void kernel_launch(void* const* d_in, const int* in_sizes, int n_in,
                              void* d_out, int out_size, void* d_ws, size_t ws_size,
                              hipStream_t stream)
{
    const float* x  = (const float*)d_in[0];
    const float* qw = (const float*)d_in[1];
    const float* kw = (const float*)d_in[2];
    const float* vw = (const float*)d_in[3];
    const float* ow = (const float*)d_in[4];

    const int BS = 8192, D = 1024, S = 2048;
    const size_t MiB = 1024 * 1024;

    char* ws = (char*)d_ws;
    __hip_bfloat16* xb  = (__hip_bfloat16*)(ws);            // dead after qkv
    __hip_bfloat16* Qb  = (__hip_bfloat16*)(ws + 16 * MiB); // also AO
    __hip_bfloat16* Kb  = (__hip_bfloat16*)(ws + 32 * MiB);
    __hip_bfloat16* Vtb = (__hip_bfloat16*)(ws + 48 * MiB);
    __hip_bfloat16* wqb = (__hip_bfloat16*)(ws + 64 * MiB);
    __hip_bfloat16* wkb = (__hip_bfloat16*)(ws + 66 * MiB);
    __hip_bfloat16* wvb = (__hip_bfloat16*)(ws + 68 * MiB);
    __hip_bfloat16* wob = (__hip_bfloat16*)(ws + 70 * MiB);
    float2* table = (float2*)(ws);                          // overlays dead xb
    const bool wbf = ws_size >= 72 * MiB;                   // fast path fits?

    dim3 blk(256);
    convert_kernel<<<(BS * D) / 2048, blk, 0, stream>>>(x, xb);
    if (wbf) {
        convert4_kernel<<<4 * (D * D) / 2048, blk, 0, stream>>>(
            qw, kw, vw, ow, wqb, wkb, wvb, wob);
        qkv_gemm<1><<<64 * 24, blk, 0, stream>>>(xb, wqb, wkb, wvb, Qb, Kb, Vtb);
    } else {
        qkv_gemm<0><<<64 * 24, blk, 0, stream>>>(xb, qw, kw, vw, Qb, Kb, Vtb);
    }
    rope_table_kernel<<<256, blk, 0, stream>>>(table);      // after qkv: xb dead
    rope2_kernel<<<2 * 16384, blk, 0, stream>>>(Qb, Kb, table);
    attn_kernel<<<4 * 16 * (S / 128), blk, 0, stream>>>(Qb, Kb, Vtb, Qb /*AO*/, S, BS);
    if (wbf) gemm_o<1><<<(BS / 128) * (D / 64), blk, 0, stream>>>(Qb, wob, (float*)d_out, BS, D, D);
    else     gemm_o<0><<<(BS / 128) * (D / 64), blk, 0, stream>>>(Qb, ow,  (float*)d_out, BS, D, D);
}

// Round 8
// 264.631 us; speedup vs baseline: 1.2121x; 1.0029x over previous
//
#include <hip/hip_runtime.h>
#include <hip/hip_bf16.h>
#include <cstdint>

// B=4, S=2048, D=1024, NH=16, DK=64. Inputs fp32, output fp32.
// Pipeline:
//   convert: xb = bf16(x); weights -> bf16 in ONE launch (fast path)
//   qkv_gemm (fused, 1536 blocks): BK=64, XOR-swizzled staging (conflict-free
//            ds_read_b128); Q|K plain stores; V -> LDS-transpose -> Vt.
//   rope_table -> rope2 (Q scale=log2e/8 and K in one launch)
//   attn: causal flash, fixed-max exp2 softmax via RAW v_exp_f32
//         (__builtin_amdgcn_exp2f), S^T-MFMA; VALU lsum + shfl epilogue.
//   gemm_o: BK=64, swizzled staging, 128x64 tiles (1024 blocks) -> fp32 out.
//
// R15 post-mortem: swizzle+BK=64 worked — qkv out of top-5 (<82us, was 84.4,
// conflicts 6.55M -> n/a). attn back to #1: 82.4us, VALU 65%, Mfma 18%.
// Counter-vs-model check: VALU busy cycles (~128k/SIMD) are ~8x the
// instruction-count estimate if exp2f were one v_exp_f32 -> libm
// __ocml_exp2_f32 expansion (~6-8 instrs: denormal range fixup) dominates
// VALU. The fixup is dead weight here: underflowed exp2 contributes 0 to
// softmax; v_exp_f32 IS exp2 over full f32 range.
// R16: p[r] = __builtin_amdgcn_exp2f(score) — raw v_exp_f32. Everything
// else untouched. Predict attn 82->~65us, VALUBusy ->~45%.

typedef __attribute__((ext_vector_type(8))) short short8;
typedef __attribute__((ext_vector_type(4))) float float4v;

#define MFMA16(a, b, c) __builtin_amdgcn_mfma_f32_16x16x32_bf16((a), (b), (c), 0, 0, 0)

__device__ __forceinline__ void glds16(const void* g, void* l) {
    __builtin_amdgcn_global_load_lds(
        (const __attribute__((address_space(1))) void*)g,
        (__attribute__((address_space(3))) void*)l, 16, 0, 0);
}

__device__ __forceinline__ unsigned int pk2(float a, float b) {
    __hip_bfloat162 h = __float22bfloat162_rn(make_float2(a, b));  // v_cvt_pk_bf16_f32
    union { __hip_bfloat162 h; unsigned int u; } v; v.h = h;
    return v.u;
}

__device__ __forceinline__ unsigned short f2bf(float x) {
    union { float f; unsigned int u; } v; v.f = x;
    unsigned int r = (v.u + 0x7FFFu + ((v.u >> 16) & 1u)) >> 16;   // RNE
    return (unsigned short)r;
}

__device__ __forceinline__ float bf2f(unsigned short b) {
    union { unsigned int u; float f; } v; v.u = ((unsigned int)b) << 16;
    return v.f;
}

// 8 contiguous fp32 -> bf16 bits (packed converts)
__device__ __forceinline__ short8 load8f(const float* p) {
    const float4 f0 = *(const float4*)p;
    const float4 f1 = *(const float4*)(p + 4);
    union { short8 s; unsigned int u[4]; } r;
    r.u[0] = pk2(f0.x, f0.y);
    r.u[1] = pk2(f0.z, f0.w);
    r.u[2] = pk2(f1.x, f1.y);
    r.u[3] = pk2(f1.z, f1.w);
    return r.s;
}

// ---------------------------------------------------------------------------
__global__ __launch_bounds__(256) void convert_kernel(
    const float* __restrict__ in, __hip_bfloat16* __restrict__ out)
{
    const int idx = (blockIdx.x * 256 + threadIdx.x) * 8;
    *(short8*)(out + idx) = load8f(in + idx);
}

// 4 weight matrices (1M elems each) in one launch: 512 blocks per matrix.
__global__ __launch_bounds__(256) void convert4_kernel(
    const float* __restrict__ a, const float* __restrict__ b,
    const float* __restrict__ c, const float* __restrict__ d,
    __hip_bfloat16* __restrict__ oa, __hip_bfloat16* __restrict__ ob,
    __hip_bfloat16* __restrict__ oc, __hip_bfloat16* __restrict__ od)
{
    const int m = blockIdx.x >> 9;
    const float* in = (m == 0) ? a : (m == 1) ? b : (m == 2) ? c : d;
    __hip_bfloat16* out = (m == 0) ? oa : (m == 1) ? ob : (m == 2) ? oc : od;
    const int idx = ((blockIdx.x & 511) * 256 + threadIdx.x) * 8;
    *(short8*)(out + idx) = load8f(in + idx);
}

// ---------------------------------------------------------------------------
__global__ __launch_bounds__(256) void rope_table_kernel(float2* __restrict__ table)
{
    const int idx = blockIdx.x * 256 + threadIdx.x;   // 65536
    const int pos = idx >> 5, fi = idx & 31;
    const float f = exp2f(-(float)fi * (13.287712379549449f / 32.0f));
    float sn, cs;
    sincosf((float)pos * f, &sn, &cs);
    table[idx] = make_float2(cs, sn);
}

// ---------------------------------------------------------------------------
// Rope in place on Q and K [8192][1024] in one launch; pairs (2i,2i+1) per
// 64-dim head, pos=row%2048. Q half gets scale=log2e/8, K half 1.0.
// ---------------------------------------------------------------------------
__global__ __launch_bounds__(256) void rope2_kernel(
    __hip_bfloat16* __restrict__ Qp, __hip_bfloat16* __restrict__ Kp,
    const float2* __restrict__ table)
{
    const int sel = blockIdx.x >> 14;                 // 0 = Q, 1 = K
    __hip_bfloat16* T = sel ? Kp : Qp;
    const float scale = sel ? 1.0f : 0.18033688011112042f;
    const int idx = (blockIdx.x & 16383) * 256 + threadIdx.x;   // 8192*512
    const int r = idx >> 9;
    const int p = idx & 511;
    const int h = p >> 5, i = p & 31;
    const float2 cs = table[(r & 2047) * 32 + i];
    unsigned short* ptr = (unsigned short*)T + (int64_t)r * 1024 + h * 64 + 2 * i;
    const ushort2 xv = *(const ushort2*)ptr;
    const float x1 = bf2f(xv.x), x2 = bf2f(xv.y);
    const unsigned int o = pk2((x1 * cs.x - x2 * cs.y) * scale,
                               (x1 * cs.y + x2 * cs.x) * scale);
    *(unsigned int*)ptr = o;
}

// ---------------------------------------------------------------------------
// Fused QKV GEMM, BK=64. A = xb [8192x1024] bf16 (glds16, pre-swizzled
// source). B = {wq,wk,wv}: BBF=1 bf16 glds16; BBF=0 fp32 register-convert.
// Staging layout: row r's col c stored at r*64 + (c ^ ((r&7)*8)) halves
// (conflict-free b128 reads). Q/K: plain store. V: swizzled LDS-transpose.
// LDS = 32768 B (A[0..8191] | B[8192..16383] halves; V-epilogue reuses all).
// ---------------------------------------------------------------------------
template<int BBF>
__global__ __launch_bounds__(256) void qkv_gemm(
    const __hip_bfloat16* __restrict__ Abf,
    const void* __restrict__ Wq, const void* __restrict__ Wk, const void* __restrict__ Wv,
    __hip_bfloat16* __restrict__ Qp, __hip_bfloat16* __restrict__ Kp,
    __hip_bfloat16* __restrict__ Vt)
{
    __shared__ unsigned short smem[128 * 128];   // 32 KiB

    const int K = 1024;
    const int bm = blockIdx.x / 24, bn = blockIdx.x % 24;
    const int widx = bn >> 3;              // 0=Q 1=K 2=V
    const int bcol0 = (bn & 7) * 128;
    const void* W = (widx == 0) ? Wq : (widx == 1) ? Wk : Wv;

    const int tid = threadIdx.x;
    const int wave = tid >> 6, lane = tid & 63;
    const int wm = (wave >> 1) * 64, wn = (wave & 1) * 64;
    const int m16 = lane & 15, quad = lane >> 4;

    const int grow = lane >> 3;                              // glds16: 8 rows/instr
    const int gcolsw = ((lane & 7) ^ (lane >> 3)) * 8;       // pre-swizzled col
    const int srow = tid >> 2, scol = (tid & 3) * 8;         // fp32 register-path

    float4v acc[4][4] = {};

    for (int k0 = 0; k0 < K; k0 += 64) {
        short8 rb[4];
        if (!BBF) {
            const float* Wf = (const float*)W;
#pragma unroll
            for (int t = 0; t < 4; t++)      // t = (rowhalf<<1)|colhalf
                rb[t] = load8f(Wf + (int64_t)(bcol0 + (t >> 1) * 64 + srow) * K
                               + k0 + (t & 1) * 32 + scol);
        }
        __syncthreads();
        {
            const __hip_bfloat16* g = Abf + (int64_t)(bm * 128 + wave * 32 + grow) * K + k0 + gcolsw;
#pragma unroll
            for (int t = 0; t < 4; t++)
                glds16(g + (int64_t)(t * 8) * K, &smem[(wave * 32 + t * 8) * 64]);
        }
        if (BBF) {
            const __hip_bfloat16* g = (const __hip_bfloat16*)W +
                (int64_t)(bcol0 + wave * 32 + grow) * K + k0 + gcolsw;
#pragma unroll
            for (int t = 0; t < 4; t++)
                glds16(g + (int64_t)(t * 8) * K, &smem[8192 + (wave * 32 + t * 8) * 64]);
        } else {
#pragma unroll
            for (int t = 0; t < 4; t++) {
                const int r = (t >> 1) * 64 + srow;
                const int c = (t & 1) * 32 + scol;
                *(short8*)&smem[8192 + r * 64 + (c ^ ((r & 7) * 8))] = rb[t];
            }
        }
        __syncthreads();

#pragma unroll
        for (int kk = 0; kk < 2; kk++) {
            const int ksw = (kk * 32 + quad * 8) ^ ((m16 & 7) * 8);
            short8 af[4], bf[4];
#pragma unroll
            for (int i = 0; i < 4; i++)
                af[i] = *(const short8*)&smem[(wm + i * 16 + m16) * 64 + ksw];
#pragma unroll
            for (int j = 0; j < 4; j++)
                bf[j] = *(const short8*)&smem[8192 + (wn + j * 16 + m16) * 64 + ksw];
#pragma unroll
            for (int i = 0; i < 4; i++)
#pragma unroll
                for (int j = 0; j < 4; j++)
                    acc[i][j] = MFMA16(af[i], bf[j], acc[i][j]);
        }
    }

    if (widx == 2) {
        // ---- V: transpose through LDS (XOR swizzle, stride 128) ----
        __syncthreads();
#pragma unroll
        for (int i = 0; i < 4; i++)
#pragma unroll
            for (int j = 0; j < 4; j++) {
                const int col = wn + j * 16 + m16;
                const int key = (col & 7) * 8;
#pragma unroll
                for (int r = 0; r < 4; r++) {
                    const int row = wm + i * 16 + quad * 4 + r;
                    smem[col * 128 + (row ^ key)] = f2bf(acc[i][j][r]);
                }
            }
        __syncthreads();
        const int dc = tid >> 4;          // 0..15
        const int seg = (tid & 15) * 8;   // 0..120 (mult of 8 -> XOR stays contiguous)
#pragma unroll
        for (int pass = 0; pass < 8; pass++) {
            const int dcol = pass * 16 + dc;
            const short8 v = *(const short8*)&smem[dcol * 128 + (seg ^ ((dcol & 7) * 8))];
            *(short8*)((unsigned short*)Vt + (int64_t)(bcol0 + dcol) * 8192 + bm * 128 + seg) = v;
        }
    } else {
        // ---- Q/K: plain store (C layout: col = lane&15, row = quad*4+r) ----
        __hip_bfloat16* dst = (widx == 0) ? Qp : Kp;
        const int row0 = bm * 128 + wm + quad * 4;
        const int col0 = bcol0 + wn + m16;
#pragma unroll
        for (int i = 0; i < 4; i++)
#pragma unroll
            for (int j = 0; j < 4; j++)
#pragma unroll
                for (int r = 0; r < 4; r++)
                    dst[(int64_t)(row0 + i * 16 + r) * 1024 + col0 + j * 16] =
                        __float2bfloat16(acc[i][j][r]);
    }
}

// ---------------------------------------------------------------------------
// Output GEMM, BK=64: C[8192][1024] fp32 = A(bf16, glds16) * B^T.
// Same swizzled staging as qkv. BM=128, BN=64 -> 1024 blocks; LDS 24 KiB.
// ---------------------------------------------------------------------------
template<int BBF>
__global__ __launch_bounds__(256) void gemm_o(
    const __hip_bfloat16* __restrict__ Abf, const void* __restrict__ B,
    float* __restrict__ C, int M, int N, int K)
{
    __shared__ __hip_bfloat16 lA[128 * 64];   // 16 KiB
    __shared__ __hip_bfloat16 lB[64 * 64];    //  8 KiB

    const int nb = N >> 6;
    const int bm = blockIdx.x / nb, bn = blockIdx.x % nb;
    const int tid = threadIdx.x;
    const int wave = tid >> 6, lane = tid & 63;
    const int wm = (wave >> 1) * 64, wn = (wave & 1) * 32;
    const int m16 = lane & 15, quad = lane >> 4;
    const int grow = lane >> 3;
    const int gcolsw = ((lane & 7) ^ (lane >> 3)) * 8;
    const int srow = tid >> 3, scol = (tid & 7) * 8;     // fp32 path: 32 rows x 64 cols

    float4v acc[4][2] = {};

    for (int k0 = 0; k0 < K; k0 += 64) {
        short8 rb[2];
        if (!BBF) {
            const float* Bf = (const float*)B;
#pragma unroll
            for (int t = 0; t < 2; t++)
                rb[t] = load8f(Bf + (int64_t)(bn * 64 + t * 32 + srow) * K + k0 + scol);
        }
        __syncthreads();
        {
            const __hip_bfloat16* g = Abf + (int64_t)(bm * 128 + wave * 32 + grow) * K + k0 + gcolsw;
#pragma unroll
            for (int t = 0; t < 4; t++)
                glds16(g + (int64_t)(t * 8) * K, &lA[(wave * 32 + t * 8) * 64]);
        }
        if (BBF) {
            const __hip_bfloat16* g = (const __hip_bfloat16*)B +
                (int64_t)(bn * 64 + wave * 16 + grow) * K + k0 + gcolsw;
#pragma unroll
            for (int t = 0; t < 2; t++)
                glds16(g + (int64_t)(t * 8) * K, &lB[(wave * 16 + t * 8) * 64]);
        } else {
#pragma unroll
            for (int t = 0; t < 2; t++) {
                const int r = t * 32 + srow;
                *(short8*)&lB[r * 64 + (scol ^ ((r & 7) * 8))] = rb[t];
            }
        }
        __syncthreads();

#pragma unroll
        for (int kk = 0; kk < 2; kk++) {
            const int ksw = (kk * 32 + quad * 8) ^ ((m16 & 7) * 8);
            short8 af[4], bf[2];
#pragma unroll
            for (int i = 0; i < 4; i++)
                af[i] = *(const short8*)&lA[(wm + i * 16 + m16) * 64 + ksw];
#pragma unroll
            for (int j = 0; j < 2; j++)
                bf[j] = *(const short8*)&lB[(wn + j * 16 + m16) * 64 + ksw];
#pragma unroll
            for (int i = 0; i < 4; i++)
#pragma unroll
                for (int j = 0; j < 2; j++)
                    acc[i][j] = MFMA16(af[i], bf[j], acc[i][j]);
        }
    }

    const int row0 = bm * 128 + wm + quad * 4;
    const int col0 = bn * 64 + wn + m16;
#pragma unroll
    for (int i = 0; i < 4; i++)
#pragma unroll
        for (int j = 0; j < 2; j++)
#pragma unroll
            for (int r = 0; r < 4; r++)
                C[(int64_t)(row0 + i * 16 + r) * N + col0 + j * 16] = acc[i][j][r];
}

// ---------------------------------------------------------------------------
// Flash attention, causal, fixed-max softmax (Q pre-scaled by log2e/8;
// p = exp2(score) via RAW v_exp_f32). Block = 4 waves x 32 Q rows = 128;
// Bc = 64. S^T-MFMA: st[mi][ni] = MFMA(K-frag, Q-frag) gives S^T in
// C-layout -> pk2 + ds_write_b64 into lP (XOR swizzle key, r-invariant).
// PV reads lP with the proven 0-conflict b128 pattern. lsum VALU-accumulated
// per (ni, m16); epilogue: 2 shuffles + shfl-gather of 1/l. VGPR 80,
// 5 blocks/CU.
// ---------------------------------------------------------------------------
__global__ __launch_bounds__(256) void attn_kernel(
    const __hip_bfloat16* __restrict__ Q,
    const __hip_bfloat16* __restrict__ Kg,
    const __hip_bfloat16* __restrict__ Vt,
    __hip_bfloat16* __restrict__ O,
    int S, int BS)
{
    // g -> qt permutation: residency groups {x, x+4, x+8, x+12} each sum to
    // 30 kt-units -> per-CU balanced; heavy blocks first. bh stays bid&63 so
    // all qt-blocks of one (b,h) keep sharing an XCD (K/V L2-local).
    const int g = blockIdx.x >> 6;        // 0..15 (S=2048)
    const int qt = (g < 4) ? 15 - g : (g < 8) ? 11 - g : (g < 12) ? g : g - 12;
    const int bh = blockIdx.x & 63;
    const int b = bh >> 4, h = bh & 15;
    const int tid = threadIdx.x;
    const int wave = tid >> 6, lane = tid & 63;
    const int m16 = lane & 15, quad = lane >> 4;

    __shared__ __hip_bfloat16 lK[64 * 64];
    __shared__ __hip_bfloat16 lV[64 * 64];        // Vt tile: [d][kv]
    __shared__ __hip_bfloat16 lP[4][32 * 64];     // total LDS = 32768 B

    const int qrow0 = qt * 128 + wave * 32;
    const int64_t rowbase = (int64_t)b * S;

    // Q frags (B-operand of the S^T MFMA): aq[ni][ks]
    short8 aq[2][2];
#pragma unroll
    for (int i = 0; i < 2; i++) {
        const __hip_bfloat16* qp = Q + (rowbase + qrow0 + i * 16 + m16) * 1024 + h * 64 + quad * 8;
        aq[i][0] = *(const short8*)qp;
        aq[i][1] = *(const short8*)(qp + 32);
    }

    float lsum[2] = {0.f, 0.f};                   // per (ni, lane m16) partials
    float4v o_acc[2][4] = {};

    const int srow = tid >> 3;
    const int scol = (tid & 7) * 8;

    const int ktmax_blk = 2 * qt + 1;
    const int ktmax_w = 2 * qt + (wave >> 1);
    const int k8 = (m16 & 7) * 8;                 // lP swizzle key (elems)

    short8 pk0, pk1, pv0, pv1;
#define PREFETCH(KT)                                                                          \
    do {                                                                                      \
        pk0 = *(const short8*)(Kg + (rowbase + (KT) * 64 + srow) * 1024 + h * 64 + scol);     \
        pk1 = *(const short8*)(Kg + (rowbase + (KT) * 64 + srow + 32) * 1024 + h * 64 + scol);\
        pv0 = *(const short8*)(Vt + (int64_t)(h * 64 + srow) * BS + rowbase + (KT) * 64 + scol);      \
        pv1 = *(const short8*)(Vt + (int64_t)(h * 64 + srow + 32) * BS + rowbase + (KT) * 64 + scol); \
    } while (0)

    PREFETCH(0);

    for (int kt = 0; kt <= ktmax_blk; kt++) {
        __syncthreads();
        *(short8*)&lK[srow * 64 + (scol ^ ((srow & 7) * 8))] = pk0;
        *(short8*)&lK[(srow + 32) * 64 + (scol ^ (((srow + 32) & 7) * 8))] = pk1;
        *(short8*)&lV[srow * 64 + (scol ^ ((srow & 7) * 8))] = pv0;
        *(short8*)&lV[(srow + 32) * 64 + (scol ^ (((srow + 32) & 7) * 8))] = pv1;
        __syncthreads();

        if (kt < ktmax_blk) PREFETCH(kt + 1);

        if (kt <= ktmax_w) {
            // S^T = K Q^T : st[mi][ni], C-layout row = kv, col = qrow
            float4v st[4][2] = {};
#pragma unroll
            for (int mi = 0; mi < 4; mi++) {
                const int n = mi * 16 + m16;
                const int sw = (n & 7) * 8;
                short8 k0 = *(const short8*)&lK[n * 64 + ((quad * 8) ^ sw)];
                short8 k1 = *(const short8*)&lK[n * 64 + ((32 + quad * 8) ^ sw)];
#pragma unroll
                for (int ni = 0; ni < 2; ni++) {
                    st[mi][ni] = MFMA16(k0, aq[ni][0], st[mi][ni]);
                    st[mi][ni] = MFMA16(k1, aq[ni][1], st[mi][ni]);
                }
            }

            // exp2 (raw v_exp_f32), causal mask, lsum, packed b64 write to lP
            const bool need_mask = (kt * 64 + 63 > qrow0);
#pragma unroll
            for (int ni = 0; ni < 2; ni++) {
                const int qg = qrow0 + ni * 16 + m16;
#pragma unroll
                for (int mi = 0; mi < 4; mi++) {
                    float p[4];
#pragma unroll
                    for (int r = 0; r < 4; r++) {
                        p[r] = __builtin_amdgcn_exp2f(st[mi][ni][r]);
                        if (need_mask) {
                            const int kvg = kt * 64 + mi * 16 + quad * 4 + r;
                            if (kvg > qg) p[r] = 0.0f;
                        }
                    }
                    lsum[ni] += (p[0] + p[1]) + (p[2] + p[3]);
                    uint2 w;
                    w.x = pk2(p[0], p[1]);
                    w.y = pk2(p[2], p[3]);
                    *(uint2*)&lP[wave][(ni * 16 + m16) * 64 + ((mi * 16 + quad * 4) ^ k8)] = w;
                }
            }

            // O += P V (lP wave-private; lgkmcnt ordering suffices)
            short8 ap[2][2];
#pragma unroll
            for (int i = 0; i < 2; i++)
#pragma unroll
                for (int ks = 0; ks < 2; ks++)
                    ap[i][ks] = *(const short8*)
                        &lP[wave][(i * 16 + m16) * 64 + ((ks * 32 + quad * 8) ^ k8)];
#pragma unroll
            for (int jd = 0; jd < 4; jd++) {
                const int d = jd * 16 + m16;
                const int sw = (d & 7) * 8;
                short8 b0 = *(const short8*)&lV[d * 64 + ((quad * 8) ^ sw)];
                short8 b1 = *(const short8*)&lV[d * 64 + ((32 + quad * 8) ^ sw)];
#pragma unroll
                for (int i = 0; i < 2; i++) {
                    o_acc[i][jd] = MFMA16(ap[i][0], b0, o_acc[i][jd]);
                    o_acc[i][jd] = MFMA16(ap[i][1], b1, o_acc[i][jd]);
                }
            }
        }
    }
#undef PREFETCH

    // l reduction: after xor16+xor32 every lane holds its m16-column's full
    // sum; invert once, then shfl-gather 1/l for the O-store lanes (no LDS).
    float rinv[2];
#pragma unroll
    for (int ni = 0; ni < 2; ni++) {
        float v = lsum[ni];
        v += __shfl_xor(v, 16);
        v += __shfl_xor(v, 32);
        rinv[ni] = 1.0f / v;
    }
    float ri[2][4];
#pragma unroll
    for (int i = 0; i < 2; i++)
#pragma unroll
        for (int r = 0; r < 4; r++)
            ri[i][r] = __shfl(rinv[i], quad * 4 + r);   // lane p holds column p

#pragma unroll
    for (int i = 0; i < 2; i++)
#pragma unroll
        for (int jd = 0; jd < 4; jd++)
#pragma unroll
            for (int r = 0; r < 4; r++) {
                const int row = qrow0 + i * 16 + quad * 4 + r;
                O[(rowbase + row) * 1024 + h * 64 + jd * 16 + m16] =
                    __float2bfloat16(o_acc[i][jd][r] * ri[i][r]);
            }
}

// ---------------------------------------------------------------------------
extern "C" void kernel_launch(void* const* d_in, const int* in_sizes, int n_in,
                              void* d_out, int out_size, void* d_ws, size_t ws_size,
                              hipStream_t stream)
{
    const float* x  = (const float*)d_in[0];
    const float* qw = (const float*)d_in[1];
    const float* kw = (const float*)d_in[2];
    const float* vw = (const float*)d_in[3];
    const float* ow = (const float*)d_in[4];

    const int BS = 8192, D = 1024, S = 2048;
    const size_t MiB = 1024 * 1024;

    char* ws = (char*)d_ws;
    __hip_bfloat16* xb  = (__hip_bfloat16*)(ws);            // dead after qkv
    __hip_bfloat16* Qb  = (__hip_bfloat16*)(ws + 16 * MiB); // also AO
    __hip_bfloat16* Kb  = (__hip_bfloat16*)(ws + 32 * MiB);
    __hip_bfloat16* Vtb = (__hip_bfloat16*)(ws + 48 * MiB);
    __hip_bfloat16* wqb = (__hip_bfloat16*)(ws + 64 * MiB);
    __hip_bfloat16* wkb = (__hip_bfloat16*)(ws + 66 * MiB);
    __hip_bfloat16* wvb = (__hip_bfloat16*)(ws + 68 * MiB);
    __hip_bfloat16* wob = (__hip_bfloat16*)(ws + 70 * MiB);
    float2* table = (float2*)(ws);                          // overlays dead xb
    const bool wbf = ws_size >= 72 * MiB;                   // fast path fits?

    dim3 blk(256);
    convert_kernel<<<(BS * D) / 2048, blk, 0, stream>>>(x, xb);
    if (wbf) {
        convert4_kernel<<<4 * (D * D) / 2048, blk, 0, stream>>>(
            qw, kw, vw, ow, wqb, wkb, wvb, wob);
        qkv_gemm<1><<<64 * 24, blk, 0, stream>>>(xb, wqb, wkb, wvb, Qb, Kb, Vtb);
    } else {
        qkv_gemm<0><<<64 * 24, blk, 0, stream>>>(xb, qw, kw, vw, Qb, Kb, Vtb);
    }
    rope_table_kernel<<<256, blk, 0, stream>>>(table);      // after qkv: xb dead
    rope2_kernel<<<2 * 16384, blk, 0, stream>>>(Qb, Kb, table);
    attn_kernel<<<4 * 16 * (S / 128), blk, 0, stream>>>(Qb, Kb, Vtb, Qb /*AO*/, S, BS);
    if (wbf) gemm_o<1><<<(BS / 128) * (D / 64), blk, 0, stream>>>(Qb, wob, (float*)d_out, BS, D, D);
    else     gemm_o<0><<<(BS / 128) * (D / 64), blk, 0, stream>>>(Qb, ow,  (float*)d_out, BS, D, D);
}

// Round 9
// 264.289 us; speedup vs baseline: 1.2136x; 1.0013x over previous
//
#include <hip/hip_runtime.h>
#include <hip/hip_bf16.h>
#include <cstdint>

// B=4, S=2048, D=1024, NH=16, DK=64. Inputs fp32, output fp32.
// Pipeline:
//   convert: xb = bf16(x); weights -> bf16 in ONE launch (fast path)
//   qkv_gemm (3072 blocks, 128x64 tiles): BK=64, XOR-swizzled staging;
//            Q|K plain stores; V -> LDS-transpose -> Vt[1024][8192].
//   rope_table -> rope2 (Q scale=log2e/8 and K in one launch)
//   attn: causal flash, fixed-max exp2 softmax via raw v_exp_f32,
//         S^T-MFMA; VALU lsum + shfl epilogue. VGPR 80, 5 blocks/CU.
//   gemm_o: BK=64, swizzled staging, 128x64 tiles (1024 blocks) -> fp32 out.
//
// R16 post-mortem: raw exp2 confirmed (attn out of top-5, <75us, was 82.4).
// qkv now #1 at 75.3us: VGPR 120 -> 4 blocks/CU resident; grid 1536 = 6
// blocks/CU over 4 slots -> batches 4+2, makespan 2t, 75% packing (Occ 19%).
// R17: qkv tile 128x128 -> 128x64: grid 3072, acc[4][2]=32 VGPR (pred ~80
// <= 85 = 512/6), LDS 24KiB -> 6 blocks/CU -> 12 half-tiles / 6 slots =
// 2 exact batches, 100% packing (makespan t). Cost: +50% A staging traffic
// (HBM 21%, headroom) and MFMA:ds 2:1 -> 1.33:1 (VALU 21%, headroom).
// gemm_o already packs exactly (1024 = 4x256) - untouched. attn untouched.

typedef __attribute__((ext_vector_type(8))) short short8;
typedef __attribute__((ext_vector_type(4))) float float4v;

#define MFMA16(a, b, c) __builtin_amdgcn_mfma_f32_16x16x32_bf16((a), (b), (c), 0, 0, 0)

__device__ __forceinline__ void glds16(const void* g, void* l) {
    __builtin_amdgcn_global_load_lds(
        (const __attribute__((address_space(1))) void*)g,
        (__attribute__((address_space(3))) void*)l, 16, 0, 0);
}

__device__ __forceinline__ unsigned int pk2(float a, float b) {
    __hip_bfloat162 h = __float22bfloat162_rn(make_float2(a, b));  // v_cvt_pk_bf16_f32
    union { __hip_bfloat162 h; unsigned int u; } v; v.h = h;
    return v.u;
}

__device__ __forceinline__ unsigned short f2bf(float x) {
    union { float f; unsigned int u; } v; v.f = x;
    unsigned int r = (v.u + 0x7FFFu + ((v.u >> 16) & 1u)) >> 16;   // RNE
    return (unsigned short)r;
}

__device__ __forceinline__ float bf2f(unsigned short b) {
    union { unsigned int u; float f; } v; v.u = ((unsigned int)b) << 16;
    return v.f;
}

// 8 contiguous fp32 -> bf16 bits (packed converts)
__device__ __forceinline__ short8 load8f(const float* p) {
    const float4 f0 = *(const float4*)p;
    const float4 f1 = *(const float4*)(p + 4);
    union { short8 s; unsigned int u[4]; } r;
    r.u[0] = pk2(f0.x, f0.y);
    r.u[1] = pk2(f0.z, f0.w);
    r.u[2] = pk2(f1.x, f1.y);
    r.u[3] = pk2(f1.z, f1.w);
    return r.s;
}

// ---------------------------------------------------------------------------
__global__ __launch_bounds__(256) void convert_kernel(
    const float* __restrict__ in, __hip_bfloat16* __restrict__ out)
{
    const int idx = (blockIdx.x * 256 + threadIdx.x) * 8;
    *(short8*)(out + idx) = load8f(in + idx);
}

// 4 weight matrices (1M elems each) in one launch: 512 blocks per matrix.
__global__ __launch_bounds__(256) void convert4_kernel(
    const float* __restrict__ a, const float* __restrict__ b,
    const float* __restrict__ c, const float* __restrict__ d,
    __hip_bfloat16* __restrict__ oa, __hip_bfloat16* __restrict__ ob,
    __hip_bfloat16* __restrict__ oc, __hip_bfloat16* __restrict__ od)
{
    const int m = blockIdx.x >> 9;
    const float* in = (m == 0) ? a : (m == 1) ? b : (m == 2) ? c : d;
    __hip_bfloat16* out = (m == 0) ? oa : (m == 1) ? ob : (m == 2) ? oc : od;
    const int idx = ((blockIdx.x & 511) * 256 + threadIdx.x) * 8;
    *(short8*)(out + idx) = load8f(in + idx);
}

// ---------------------------------------------------------------------------
__global__ __launch_bounds__(256) void rope_table_kernel(float2* __restrict__ table)
{
    const int idx = blockIdx.x * 256 + threadIdx.x;   // 65536
    const int pos = idx >> 5, fi = idx & 31;
    const float f = exp2f(-(float)fi * (13.287712379549449f / 32.0f));
    float sn, cs;
    sincosf((float)pos * f, &sn, &cs);
    table[idx] = make_float2(cs, sn);
}

// ---------------------------------------------------------------------------
// Rope in place on Q and K [8192][1024] in one launch; pairs (2i,2i+1) per
// 64-dim head, pos=row%2048. Q half gets scale=log2e/8, K half 1.0.
// ---------------------------------------------------------------------------
__global__ __launch_bounds__(256) void rope2_kernel(
    __hip_bfloat16* __restrict__ Qp, __hip_bfloat16* __restrict__ Kp,
    const float2* __restrict__ table)
{
    const int sel = blockIdx.x >> 14;                 // 0 = Q, 1 = K
    __hip_bfloat16* T = sel ? Kp : Qp;
    const float scale = sel ? 1.0f : 0.18033688011112042f;
    const int idx = (blockIdx.x & 16383) * 256 + threadIdx.x;   // 8192*512
    const int r = idx >> 9;
    const int p = idx & 511;
    const int h = p >> 5, i = p & 31;
    const float2 cs = table[(r & 2047) * 32 + i];
    unsigned short* ptr = (unsigned short*)T + (int64_t)r * 1024 + h * 64 + 2 * i;
    const ushort2 xv = *(const ushort2*)ptr;
    const float x1 = bf2f(xv.x), x2 = bf2f(xv.y);
    const unsigned int o = pk2((x1 * cs.x - x2 * cs.y) * scale,
                               (x1 * cs.y + x2 * cs.x) * scale);
    *(unsigned int*)ptr = o;
}

// ---------------------------------------------------------------------------
// Fused QKV GEMM, 128x64 tiles, BK=64. Grid = 64 bm x 48 bn (3 matrices x
// 16 col-blocks). A = xb bf16 (glds16, pre-swizzled source). B: BBF=1 bf16
// glds16; BBF=0 fp32 register-convert. Staging: row r col c at
// r*64 + (c ^ ((r&7)*8)) halves. LDS 24 KiB -> 6 blocks/CU; acc[4][2]
// keeps VGPR ~80 -> 6 waves/SIMD -> 12 half-tiles / 6 slots = exact batches.
// ---------------------------------------------------------------------------
template<int BBF>
__global__ __launch_bounds__(256) void qkv_gemm(
    const __hip_bfloat16* __restrict__ Abf,
    const void* __restrict__ Wq, const void* __restrict__ Wk, const void* __restrict__ Wv,
    __hip_bfloat16* __restrict__ Qp, __hip_bfloat16* __restrict__ Kp,
    __hip_bfloat16* __restrict__ Vt)
{
    __shared__ unsigned short smem[12288];   // A[0..8191] | B[8192..12287]; 24 KiB

    const int K = 1024;
    const int bm = blockIdx.x / 48, bn = blockIdx.x % 48;
    const int widx = bn >> 4;              // 0=Q 1=K 2=V
    const int bcol0 = (bn & 15) * 64;
    const void* W = (widx == 0) ? Wq : (widx == 1) ? Wk : Wv;

    const int tid = threadIdx.x;
    const int wave = tid >> 6, lane = tid & 63;
    const int wm = (wave >> 1) * 64, wn = (wave & 1) * 32;
    const int m16 = lane & 15, quad = lane >> 4;

    const int grow = lane >> 3;                              // glds16: 8 rows/instr
    const int gcolsw = ((lane & 7) ^ (lane >> 3)) * 8;       // pre-swizzled col
    const int srow = tid >> 3, scol = (tid & 7) * 8;         // fp32 register-path

    float4v acc[4][2] = {};

    for (int k0 = 0; k0 < K; k0 += 64) {
        short8 rb[2];
        if (!BBF) {
            const float* Wf = (const float*)W;
#pragma unroll
            for (int t = 0; t < 2; t++)
                rb[t] = load8f(Wf + (int64_t)(bcol0 + t * 32 + srow) * K + k0 + scol);
        }
        __syncthreads();
        {
            const __hip_bfloat16* g = Abf + (int64_t)(bm * 128 + wave * 32 + grow) * K + k0 + gcolsw;
#pragma unroll
            for (int t = 0; t < 4; t++)
                glds16(g + (int64_t)(t * 8) * K, &smem[(wave * 32 + t * 8) * 64]);
        }
        if (BBF) {
            const __hip_bfloat16* g = (const __hip_bfloat16*)W +
                (int64_t)(bcol0 + wave * 16 + grow) * K + k0 + gcolsw;
#pragma unroll
            for (int t = 0; t < 2; t++)
                glds16(g + (int64_t)(t * 8) * K, &smem[8192 + (wave * 16 + t * 8) * 64]);
        } else {
#pragma unroll
            for (int t = 0; t < 2; t++) {
                const int r = t * 32 + srow;
                *(short8*)&smem[8192 + r * 64 + (scol ^ ((r & 7) * 8))] = rb[t];
            }
        }
        __syncthreads();

#pragma unroll
        for (int kk = 0; kk < 2; kk++) {
            const int ksw = (kk * 32 + quad * 8) ^ ((m16 & 7) * 8);
            short8 af[4], bf[2];
#pragma unroll
            for (int i = 0; i < 4; i++)
                af[i] = *(const short8*)&smem[(wm + i * 16 + m16) * 64 + ksw];
#pragma unroll
            for (int j = 0; j < 2; j++)
                bf[j] = *(const short8*)&smem[8192 + (wn + j * 16 + m16) * 64 + ksw];
#pragma unroll
            for (int i = 0; i < 4; i++)
#pragma unroll
                for (int j = 0; j < 2; j++)
                    acc[i][j] = MFMA16(af[i], bf[j], acc[i][j]);
        }
    }

    if (widx == 2) {
        // ---- V: transpose through LDS (XOR swizzle, stride 128); 16 KiB ----
        __syncthreads();
#pragma unroll
        for (int i = 0; i < 4; i++)
#pragma unroll
            for (int j = 0; j < 2; j++) {
                const int col = wn + j * 16 + m16;          // 0..63
                const int key = (col & 7) * 8;
#pragma unroll
                for (int r = 0; r < 4; r++) {
                    const int row = wm + i * 16 + quad * 4 + r;
                    smem[col * 128 + (row ^ key)] = f2bf(acc[i][j][r]);
                }
            }
        __syncthreads();
        const int dc = tid >> 4;          // 0..15
        const int seg = (tid & 15) * 8;   // 0..120 (mult of 8 -> XOR stays contiguous)
#pragma unroll
        for (int pass = 0; pass < 4; pass++) {
            const int dcol = pass * 16 + dc;                // 0..63
            const short8 v = *(const short8*)&smem[dcol * 128 + (seg ^ ((dcol & 7) * 8))];
            *(short8*)((unsigned short*)Vt + (int64_t)(bcol0 + dcol) * 8192 + bm * 128 + seg) = v;
        }
    } else {
        // ---- Q/K: plain store (C layout: col = lane&15, row = quad*4+r) ----
        __hip_bfloat16* dst = (widx == 0) ? Qp : Kp;
        const int row0 = bm * 128 + wm + quad * 4;
        const int col0 = bcol0 + wn + m16;
#pragma unroll
        for (int i = 0; i < 4; i++)
#pragma unroll
            for (int j = 0; j < 2; j++)
#pragma unroll
                for (int r = 0; r < 4; r++)
                    dst[(int64_t)(row0 + i * 16 + r) * 1024 + col0 + j * 16] =
                        __float2bfloat16(acc[i][j][r]);
    }
}

// ---------------------------------------------------------------------------
// Output GEMM, BK=64: C[8192][1024] fp32 = A(bf16, glds16) * B^T.
// Swizzled staging. BM=128, BN=64 -> 1024 blocks (exact 4/CU batch).
// ---------------------------------------------------------------------------
template<int BBF>
__global__ __launch_bounds__(256) void gemm_o(
    const __hip_bfloat16* __restrict__ Abf, const void* __restrict__ B,
    float* __restrict__ C, int M, int N, int K)
{
    __shared__ __hip_bfloat16 lA[128 * 64];   // 16 KiB
    __shared__ __hip_bfloat16 lB[64 * 64];    //  8 KiB

    const int nb = N >> 6;
    const int bm = blockIdx.x / nb, bn = blockIdx.x % nb;
    const int tid = threadIdx.x;
    const int wave = tid >> 6, lane = tid & 63;
    const int wm = (wave >> 1) * 64, wn = (wave & 1) * 32;
    const int m16 = lane & 15, quad = lane >> 4;
    const int grow = lane >> 3;
    const int gcolsw = ((lane & 7) ^ (lane >> 3)) * 8;
    const int srow = tid >> 3, scol = (tid & 7) * 8;     // fp32 path: 32 rows x 64 cols

    float4v acc[4][2] = {};

    for (int k0 = 0; k0 < K; k0 += 64) {
        short8 rb[2];
        if (!BBF) {
            const float* Bf = (const float*)B;
#pragma unroll
            for (int t = 0; t < 2; t++)
                rb[t] = load8f(Bf + (int64_t)(bn * 64 + t * 32 + srow) * K + k0 + scol);
        }
        __syncthreads();
        {
            const __hip_bfloat16* g = Abf + (int64_t)(bm * 128 + wave * 32 + grow) * K + k0 + gcolsw;
#pragma unroll
            for (int t = 0; t < 4; t++)
                glds16(g + (int64_t)(t * 8) * K, &lA[(wave * 32 + t * 8) * 64]);
        }
        if (BBF) {
            const __hip_bfloat16* g = (const __hip_bfloat16*)B +
                (int64_t)(bn * 64 + wave * 16 + grow) * K + k0 + gcolsw;
#pragma unroll
            for (int t = 0; t < 2; t++)
                glds16(g + (int64_t)(t * 8) * K, &lB[(wave * 16 + t * 8) * 64]);
        } else {
#pragma unroll
            for (int t = 0; t < 2; t++) {
                const int r = t * 32 + srow;
                *(short8*)&lB[r * 64 + (scol ^ ((r & 7) * 8))] = rb[t];
            }
        }
        __syncthreads();

#pragma unroll
        for (int kk = 0; kk < 2; kk++) {
            const int ksw = (kk * 32 + quad * 8) ^ ((m16 & 7) * 8);
            short8 af[4], bf[2];
#pragma unroll
            for (int i = 0; i < 4; i++)
                af[i] = *(const short8*)&lA[(wm + i * 16 + m16) * 64 + ksw];
#pragma unroll
            for (int j = 0; j < 2; j++)
                bf[j] = *(const short8*)&lB[(wn + j * 16 + m16) * 64 + ksw];
#pragma unroll
            for (int i = 0; i < 4; i++)
#pragma unroll
                for (int j = 0; j < 2; j++)
                    acc[i][j] = MFMA16(af[i], bf[j], acc[i][j]);
        }
    }

    const int row0 = bm * 128 + wm + quad * 4;
    const int col0 = bn * 64 + wn + m16;
#pragma unroll
    for (int i = 0; i < 4; i++)
#pragma unroll
        for (int j = 0; j < 2; j++)
#pragma unroll
            for (int r = 0; r < 4; r++)
                C[(int64_t)(row0 + i * 16 + r) * N + col0 + j * 16] = acc[i][j][r];
}

// ---------------------------------------------------------------------------
// Flash attention, causal, fixed-max softmax (Q pre-scaled by log2e/8;
// p = exp2(score) via RAW v_exp_f32). Block = 4 waves x 32 Q rows = 128;
// Bc = 64. S^T-MFMA: st[mi][ni] = MFMA(K-frag, Q-frag) gives S^T in
// C-layout -> pk2 + ds_write_b64 into lP (XOR swizzle key, r-invariant).
// PV reads lP with the proven 0-conflict b128 pattern. lsum VALU-accumulated
// per (ni, m16); epilogue: 2 shuffles + shfl-gather of 1/l. VGPR 80,
// 5 blocks/CU.
// ---------------------------------------------------------------------------
__global__ __launch_bounds__(256) void attn_kernel(
    const __hip_bfloat16* __restrict__ Q,
    const __hip_bfloat16* __restrict__ Kg,
    const __hip_bfloat16* __restrict__ Vt,
    __hip_bfloat16* __restrict__ O,
    int S, int BS)
{
    // g -> qt permutation: residency groups {x, x+4, x+8, x+12} each sum to
    // 30 kt-units -> per-CU balanced; heavy blocks first. bh stays bid&63 so
    // all qt-blocks of one (b,h) keep sharing an XCD (K/V L2-local).
    const int g = blockIdx.x >> 6;        // 0..15 (S=2048)
    const int qt = (g < 4) ? 15 - g : (g < 8) ? 11 - g : (g < 12) ? g : g - 12;
    const int bh = blockIdx.x & 63;
    const int b = bh >> 4, h = bh & 15;
    const int tid = threadIdx.x;
    const int wave = tid >> 6, lane = tid & 63;
    const int m16 = lane & 15, quad = lane >> 4;

    __shared__ __hip_bfloat16 lK[64 * 64];
    __shared__ __hip_bfloat16 lV[64 * 64];        // Vt tile: [d][kv]
    __shared__ __hip_bfloat16 lP[4][32 * 64];     // total LDS = 32768 B

    const int qrow0 = qt * 128 + wave * 32;
    const int64_t rowbase = (int64_t)b * S;

    // Q frags (B-operand of the S^T MFMA): aq[ni][ks]
    short8 aq[2][2];
#pragma unroll
    for (int i = 0; i < 2; i++) {
        const __hip_bfloat16* qp = Q + (rowbase + qrow0 + i * 16 + m16) * 1024 + h * 64 + quad * 8;
        aq[i][0] = *(const short8*)qp;
        aq[i][1] = *(const short8*)(qp + 32);
    }

    float lsum[2] = {0.f, 0.f};                   // per (ni, lane m16) partials
    float4v o_acc[2][4] = {};

    const int srow = tid >> 3;
    const int scol = (tid & 7) * 8;

    const int ktmax_blk = 2 * qt + 1;
    const int ktmax_w = 2 * qt + (wave >> 1);
    const int k8 = (m16 & 7) * 8;                 // lP swizzle key (elems)

    short8 pk0, pk1, pv0, pv1;
#define PREFETCH(KT)                                                                          \
    do {                                                                                      \
        pk0 = *(const short8*)(Kg + (rowbase + (KT) * 64 + srow) * 1024 + h * 64 + scol);     \
        pk1 = *(const short8*)(Kg + (rowbase + (KT) * 64 + srow + 32) * 1024 + h * 64 + scol);\
        pv0 = *(const short8*)(Vt + (int64_t)(h * 64 + srow) * BS + rowbase + (KT) * 64 + scol);      \
        pv1 = *(const short8*)(Vt + (int64_t)(h * 64 + srow + 32) * BS + rowbase + (KT) * 64 + scol); \
    } while (0)

    PREFETCH(0);

    for (int kt = 0; kt <= ktmax_blk; kt++) {
        __syncthreads();
        *(short8*)&lK[srow * 64 + (scol ^ ((srow & 7) * 8))] = pk0;
        *(short8*)&lK[(srow + 32) * 64 + (scol ^ (((srow + 32) & 7) * 8))] = pk1;
        *(short8*)&lV[srow * 64 + (scol ^ ((srow & 7) * 8))] = pv0;
        *(short8*)&lV[(srow + 32) * 64 + (scol ^ (((srow + 32) & 7) * 8))] = pv1;
        __syncthreads();

        if (kt < ktmax_blk) PREFETCH(kt + 1);

        if (kt <= ktmax_w) {
            // S^T = K Q^T : st[mi][ni], C-layout row = kv, col = qrow
            float4v st[4][2] = {};
#pragma unroll
            for (int mi = 0; mi < 4; mi++) {
                const int n = mi * 16 + m16;
                const int sw = (n & 7) * 8;
                short8 k0 = *(const short8*)&lK[n * 64 + ((quad * 8) ^ sw)];
                short8 k1 = *(const short8*)&lK[n * 64 + ((32 + quad * 8) ^ sw)];
#pragma unroll
                for (int ni = 0; ni < 2; ni++) {
                    st[mi][ni] = MFMA16(k0, aq[ni][0], st[mi][ni]);
                    st[mi][ni] = MFMA16(k1, aq[ni][1], st[mi][ni]);
                }
            }

            // exp2 (raw v_exp_f32), causal mask, lsum, packed b64 write to lP
            const bool need_mask = (kt * 64 + 63 > qrow0);
#pragma unroll
            for (int ni = 0; ni < 2; ni++) {
                const int qg = qrow0 + ni * 16 + m16;
#pragma unroll
                for (int mi = 0; mi < 4; mi++) {
                    float p[4];
#pragma unroll
                    for (int r = 0; r < 4; r++) {
                        p[r] = __builtin_amdgcn_exp2f(st[mi][ni][r]);
                        if (need_mask) {
                            const int kvg = kt * 64 + mi * 16 + quad * 4 + r;
                            if (kvg > qg) p[r] = 0.0f;
                        }
                    }
                    lsum[ni] += (p[0] + p[1]) + (p[2] + p[3]);
                    uint2 w;
                    w.x = pk2(p[0], p[1]);
                    w.y = pk2(p[2], p[3]);
                    *(uint2*)&lP[wave][(ni * 16 + m16) * 64 + ((mi * 16 + quad * 4) ^ k8)] = w;
                }
            }

            // O += P V (lP wave-private; lgkmcnt ordering suffices)
            short8 ap[2][2];
#pragma unroll
            for (int i = 0; i < 2; i++)
#pragma unroll
                for (int ks = 0; ks < 2; ks++)
                    ap[i][ks] = *(const short8*)
                        &lP[wave][(i * 16 + m16) * 64 + ((ks * 32 + quad * 8) ^ k8)];
#pragma unroll
            for (int jd = 0; jd < 4; jd++) {
                const int d = jd * 16 + m16;
                const int sw = (d & 7) * 8;
                short8 b0 = *(const short8*)&lV[d * 64 + ((quad * 8) ^ sw)];
                short8 b1 = *(const short8*)&lV[d * 64 + ((32 + quad * 8) ^ sw)];
#pragma unroll
                for (int i = 0; i < 2; i++) {
                    o_acc[i][jd] = MFMA16(ap[i][0], b0, o_acc[i][jd]);
                    o_acc[i][jd] = MFMA16(ap[i][1], b1, o_acc[i][jd]);
                }
            }
        }
    }
#undef PREFETCH

    // l reduction: after xor16+xor32 every lane holds its m16-column's full
    // sum; invert once, then shfl-gather 1/l for the O-store lanes (no LDS).
    float rinv[2];
#pragma unroll
    for (int ni = 0; ni < 2; ni++) {
        float v = lsum[ni];
        v += __shfl_xor(v, 16);
        v += __shfl_xor(v, 32);
        rinv[ni] = 1.0f / v;
    }
    float ri[2][4];
#pragma unroll
    for (int i = 0; i < 2; i++)
#pragma unroll
        for (int r = 0; r < 4; r++)
            ri[i][r] = __shfl(rinv[i], quad * 4 + r);   // lane p holds column p

#pragma unroll
    for (int i = 0; i < 2; i++)
#pragma unroll
        for (int jd = 0; jd < 4; jd++)
#pragma unroll
            for (int r = 0; r < 4; r++) {
                const int row = qrow0 + i * 16 + quad * 4 + r;
                O[(rowbase + row) * 1024 + h * 64 + jd * 16 + m16] =
                    __float2bfloat16(o_acc[i][jd][r] * ri[i][r]);
            }
}

// ---------------------------------------------------------------------------
extern "C" void kernel_launch(void* const* d_in, const int* in_sizes, int n_in,
                              void* d_out, int out_size, void* d_ws, size_t ws_size,
                              hipStream_t stream)
{
    const float* x  = (const float*)d_in[0];
    const float* qw = (const float*)d_in[1];
    const float* kw = (const float*)d_in[2];
    const float* vw = (const float*)d_in[3];
    const float* ow = (const float*)d_in[4];

    const int BS = 8192, D = 1024, S = 2048;
    const size_t MiB = 1024 * 1024;

    char* ws = (char*)d_ws;
    __hip_bfloat16* xb  = (__hip_bfloat16*)(ws);            // dead after qkv
    __hip_bfloat16* Qb  = (__hip_bfloat16*)(ws + 16 * MiB); // also AO
    __hip_bfloat16* Kb  = (__hip_bfloat16*)(ws + 32 * MiB);
    __hip_bfloat16* Vtb = (__hip_bfloat16*)(ws + 48 * MiB);
    __hip_bfloat16* wqb = (__hip_bfloat16*)(ws + 64 * MiB);
    __hip_bfloat16* wkb = (__hip_bfloat16*)(ws + 66 * MiB);
    __hip_bfloat16* wvb = (__hip_bfloat16*)(ws + 68 * MiB);
    __hip_bfloat16* wob = (__hip_bfloat16*)(ws + 70 * MiB);
    float2* table = (float2*)(ws);                          // overlays dead xb
    const bool wbf = ws_size >= 72 * MiB;                   // fast path fits?

    dim3 blk(256);
    convert_kernel<<<(BS * D) / 2048, blk, 0, stream>>>(x, xb);
    if (wbf) {
        convert4_kernel<<<4 * (D * D) / 2048, blk, 0, stream>>>(
            qw, kw, vw, ow, wqb, wkb, wvb, wob);
        qkv_gemm<1><<<64 * 48, blk, 0, stream>>>(xb, wqb, wkb, wvb, Qb, Kb, Vtb);
    } else {
        qkv_gemm<0><<<64 * 48, blk, 0, stream>>>(xb, qw, kw, vw, Qb, Kb, Vtb);
    }
    rope_table_kernel<<<256, blk, 0, stream>>>(table);      // after qkv: xb dead
    rope2_kernel<<<2 * 16384, blk, 0, stream>>>(Qb, Kb, table);
    attn_kernel<<<4 * 16 * (S / 128), blk, 0, stream>>>(Qb, Kb, Vtb, Qb /*AO*/, S, BS);
    if (wbf) gemm_o<1><<<(BS / 128) * (D / 64), blk, 0, stream>>>(Qb, wob, (float*)d_out, BS, D, D);
    else     gemm_o<0><<<(BS / 128) * (D / 64), blk, 0, stream>>>(Qb, ow,  (float*)d_out, BS, D, D);
}

// Round 11
// 247.642 us; speedup vs baseline: 1.2952x; 1.0672x over previous
//
#include <hip/hip_runtime.h>
#include <hip/hip_bf16.h>
#include <cstdint>

// B=4, S=2048, D=1024, NH=16, DK=64. Inputs fp32, output fp32.
// Pipeline (5 launches):
//   convert_x_table: xb = bf16(x) + rope cos/sin table (into d_out tail)
//   convert4: weights -> bf16 (fast path)
//   qkv_gemm (3072 blocks, 128x64, BK=64, swizzled): Q|K stores WITH ROPE
//            fused in epilogue (shfl_xor(1) pair exchange); V -> Vt transpose.
//   attn: causal flash, raw-v_exp_f32 softmax, S^T-MFMA. UNTOUCHED.
//   gemm_o: BK=64, swizzled, 128x64 tiles -> fp32 out.
//
// R18 (resubmit; R18 bench failed on container acquisition): fuse rope into
// qkv epilogue. Pair partner (col^1) is lane m16^1 -> one __shfl_xor;
// parity (m16&1) lane-uniform: out = v*cos + sgn*vp*sin. Table in d_out
// tail (+31MiB, 512KB; dead before gemm_o writes), computed in the convert
// launch. Kills rope2 + rope_table + 2 gaps. Audited: pair/sign/freq
// mapping, block-uniform branch around shfl, table lifetime.
// Gate: absmax must stay 0.0156 else rope mapping wrong -> revert.

typedef __attribute__((ext_vector_type(8))) short short8;
typedef __attribute__((ext_vector_type(4))) float float4v;

#define MFMA16(a, b, c) __builtin_amdgcn_mfma_f32_16x16x32_bf16((a), (b), (c), 0, 0, 0)

__device__ __forceinline__ void glds16(const void* g, void* l) {
    __builtin_amdgcn_global_load_lds(
        (const __attribute__((address_space(1))) void*)g,
        (__attribute__((address_space(3))) void*)l, 16, 0, 0);
}

__device__ __forceinline__ unsigned int pk2(float a, float b) {
    __hip_bfloat162 h = __float22bfloat162_rn(make_float2(a, b));  // v_cvt_pk_bf16_f32
    union { __hip_bfloat162 h; unsigned int u; } v; v.h = h;
    return v.u;
}

__device__ __forceinline__ unsigned short f2bf(float x) {
    union { float f; unsigned int u; } v; v.f = x;
    unsigned int r = (v.u + 0x7FFFu + ((v.u >> 16) & 1u)) >> 16;   // RNE
    return (unsigned short)r;
}

__device__ __forceinline__ float bf2f(unsigned short b) {
    union { unsigned int u; float f; } v; v.u = ((unsigned int)b) << 16;
    return v.f;
}

// 8 contiguous fp32 -> bf16 bits (packed converts)
__device__ __forceinline__ short8 load8f(const float* p) {
    const float4 f0 = *(const float4*)p;
    const float4 f1 = *(const float4*)(p + 4);
    union { short8 s; unsigned int u[4]; } r;
    r.u[0] = pk2(f0.x, f0.y);
    r.u[1] = pk2(f0.z, f0.w);
    r.u[2] = pk2(f1.x, f1.y);
    r.u[3] = pk2(f1.z, f1.w);
    return r.s;
}

// ---------------------------------------------------------------------------
// x -> bf16 (blocks 0..4095) + rope table (blocks 4096..4351, into d_out tail)
__global__ __launch_bounds__(256) void convert_x_table(
    const float* __restrict__ in, __hip_bfloat16* __restrict__ out,
    float2* __restrict__ table)
{
    if (blockIdx.x < 4096) {
        const int idx = (blockIdx.x * 256 + threadIdx.x) * 8;
        *(short8*)(out + idx) = load8f(in + idx);
    } else {
        const int idx = (blockIdx.x - 4096) * 256 + threadIdx.x;   // 65536
        const int pos = idx >> 5, fi = idx & 31;
        const float f = exp2f(-(float)fi * (13.287712379549449f / 32.0f));
        float sn, cs;
        sincosf((float)pos * f, &sn, &cs);
        table[idx] = make_float2(cs, sn);
    }
}

// 4 weight matrices (1M elems each) in one launch: 512 blocks per matrix.
__global__ __launch_bounds__(256) void convert4_kernel(
    const float* __restrict__ a, const float* __restrict__ b,
    const float* __restrict__ c, const float* __restrict__ d,
    __hip_bfloat16* __restrict__ oa, __hip_bfloat16* __restrict__ ob,
    __hip_bfloat16* __restrict__ oc, __hip_bfloat16* __restrict__ od)
{
    const int m = blockIdx.x >> 9;
    const float* in = (m == 0) ? a : (m == 1) ? b : (m == 2) ? c : d;
    __hip_bfloat16* out = (m == 0) ? oa : (m == 1) ? ob : (m == 2) ? oc : od;
    const int idx = ((blockIdx.x & 511) * 256 + threadIdx.x) * 8;
    *(short8*)(out + idx) = load8f(in + idx);
}

// ---------------------------------------------------------------------------
// Fused QKV GEMM, 128x64 tiles, BK=64, swizzled staging. Grid 64bm x 48bn.
// Q/K epilogue applies ROPE from registers: partner col^1 = lane m16^1 via
// __shfl_xor(v,1); parity m16&1 lane-uniform; Q pre-scaled by log2e/8.
// V -> swizzled LDS transpose -> Vt[1024][8192]. LDS 24 KiB, acc[4][2].
// ---------------------------------------------------------------------------
template<int BBF>
__global__ __launch_bounds__(256) void qkv_gemm(
    const __hip_bfloat16* __restrict__ Abf,
    const void* __restrict__ Wq, const void* __restrict__ Wk, const void* __restrict__ Wv,
    __hip_bfloat16* __restrict__ Qp, __hip_bfloat16* __restrict__ Kp,
    __hip_bfloat16* __restrict__ Vt, const float2* __restrict__ table)
{
    __shared__ unsigned short smem[12288];   // A[0..8191] | B[8192..12287]; 24 KiB

    const int K = 1024;
    const int bm = blockIdx.x / 48, bn = blockIdx.x % 48;
    const int widx = bn >> 4;              // 0=Q 1=K 2=V
    const int bcol0 = (bn & 15) * 64;
    const void* W = (widx == 0) ? Wq : (widx == 1) ? Wk : Wv;

    const int tid = threadIdx.x;
    const int wave = tid >> 6, lane = tid & 63;
    const int wm = (wave >> 1) * 64, wn = (wave & 1) * 32;
    const int m16 = lane & 15, quad = lane >> 4;

    const int grow = lane >> 3;                              // glds16: 8 rows/instr
    const int gcolsw = ((lane & 7) ^ (lane >> 3)) * 8;       // pre-swizzled col
    const int srow = tid >> 3, scol = (tid & 7) * 8;         // fp32 register-path

    float4v acc[4][2] = {};

    for (int k0 = 0; k0 < K; k0 += 64) {
        short8 rb[2];
        if (!BBF) {
            const float* Wf = (const float*)W;
#pragma unroll
            for (int t = 0; t < 2; t++)
                rb[t] = load8f(Wf + (int64_t)(bcol0 + t * 32 + srow) * K + k0 + scol);
        }
        __syncthreads();
        {
            const __hip_bfloat16* g = Abf + (int64_t)(bm * 128 + wave * 32 + grow) * K + k0 + gcolsw;
#pragma unroll
            for (int t = 0; t < 4; t++)
                glds16(g + (int64_t)(t * 8) * K, &smem[(wave * 32 + t * 8) * 64]);
        }
        if (BBF) {
            const __hip_bfloat16* g = (const __hip_bfloat16*)W +
                (int64_t)(bcol0 + wave * 16 + grow) * K + k0 + gcolsw;
#pragma unroll
            for (int t = 0; t < 2; t++)
                glds16(g + (int64_t)(t * 8) * K, &smem[8192 + (wave * 16 + t * 8) * 64]);
        } else {
#pragma unroll
            for (int t = 0; t < 2; t++) {
                const int r = t * 32 + srow;
                *(short8*)&smem[8192 + r * 64 + (scol ^ ((r & 7) * 8))] = rb[t];
            }
        }
        __syncthreads();

#pragma unroll
        for (int kk = 0; kk < 2; kk++) {
            const int ksw = (kk * 32 + quad * 8) ^ ((m16 & 7) * 8);
            short8 af[4], bf[2];
#pragma unroll
            for (int i = 0; i < 4; i++)
                af[i] = *(const short8*)&smem[(wm + i * 16 + m16) * 64 + ksw];
#pragma unroll
            for (int j = 0; j < 2; j++)
                bf[j] = *(const short8*)&smem[8192 + (wn + j * 16 + m16) * 64 + ksw];
#pragma unroll
            for (int i = 0; i < 4; i++)
#pragma unroll
                for (int j = 0; j < 2; j++)
                    acc[i][j] = MFMA16(af[i], bf[j], acc[i][j]);
        }
    }

    if (widx == 2) {
        // ---- V: transpose through LDS (XOR swizzle, stride 128); 16 KiB ----
        __syncthreads();
#pragma unroll
        for (int i = 0; i < 4; i++)
#pragma unroll
            for (int j = 0; j < 2; j++) {
                const int col = wn + j * 16 + m16;          // 0..63
                const int key = (col & 7) * 8;
#pragma unroll
                for (int r = 0; r < 4; r++) {
                    const int row = wm + i * 16 + quad * 4 + r;
                    smem[col * 128 + (row ^ key)] = f2bf(acc[i][j][r]);
                }
            }
        __syncthreads();
        const int dc = tid >> 4;          // 0..15
        const int seg = (tid & 15) * 8;   // 0..120 (mult of 8 -> XOR stays contiguous)
#pragma unroll
        for (int pass = 0; pass < 4; pass++) {
            const int dcol = pass * 16 + dc;                // 0..63
            const short8 v = *(const short8*)&smem[dcol * 128 + (seg ^ ((dcol & 7) * 8))];
            *(short8*)((unsigned short*)Vt + (int64_t)(bcol0 + dcol) * 8192 + bm * 128 + seg) = v;
        }
    } else {
        // ---- Q/K: ROPE in registers, then plain store ----
        // C layout: col = col0 + j*16 (parity = m16&1, lane-uniform);
        // partner value (col^1) sits in lane^1. out = v*cos + sgn*vp*sin.
        __hip_bfloat16* dst = (widx == 0) ? Qp : Kp;
        const float scale = (widx == 0) ? 0.18033688011112042f : 1.0f;
        const float sgn = (m16 & 1) ? 1.0f : -1.0f;
        const int row0 = bm * 128 + wm + quad * 4;
        const int col0 = bcol0 + wn + m16;
#pragma unroll
        for (int i = 0; i < 4; i++)
#pragma unroll
            for (int j = 0; j < 2; j++) {
                const int ifq = ((wn + j * 16 + m16) & 63) >> 1;   // pair idx in head
#pragma unroll
                for (int r = 0; r < 4; r++) {
                    const float v = acc[i][j][r] * scale;
                    const float vp = __shfl_xor(v, 1);
                    const int row = row0 + i * 16 + r;
                    const float2 cs = table[(row & 2047) * 32 + ifq];
                    const float out = v * cs.x + sgn * vp * cs.y;
                    dst[(int64_t)row * 1024 + col0 + j * 16] = __float2bfloat16(out);
                }
            }
    }
}

// ---------------------------------------------------------------------------
// Output GEMM, BK=64: C[8192][1024] fp32 = A(bf16, glds16) * B^T.
// Swizzled staging. BM=128, BN=64 -> 1024 blocks (exact 4/CU batch).
// ---------------------------------------------------------------------------
template<int BBF>
__global__ __launch_bounds__(256) void gemm_o(
    const __hip_bfloat16* __restrict__ Abf, const void* __restrict__ B,
    float* __restrict__ C, int M, int N, int K)
{
    __shared__ __hip_bfloat16 lA[128 * 64];   // 16 KiB
    __shared__ __hip_bfloat16 lB[64 * 64];    //  8 KiB

    const int nb = N >> 6;
    const int bm = blockIdx.x / nb, bn = blockIdx.x % nb;
    const int tid = threadIdx.x;
    const int wave = tid >> 6, lane = tid & 63;
    const int wm = (wave >> 1) * 64, wn = (wave & 1) * 32;
    const int m16 = lane & 15, quad = lane >> 4;
    const int grow = lane >> 3;
    const int gcolsw = ((lane & 7) ^ (lane >> 3)) * 8;
    const int srow = tid >> 3, scol = (tid & 7) * 8;     // fp32 path: 32 rows x 64 cols

    float4v acc[4][2] = {};

    for (int k0 = 0; k0 < K; k0 += 64) {
        short8 rb[2];
        if (!BBF) {
            const float* Bf = (const float*)B;
#pragma unroll
            for (int t = 0; t < 2; t++)
                rb[t] = load8f(Bf + (int64_t)(bn * 64 + t * 32 + srow) * K + k0 + scol);
        }
        __syncthreads();
        {
            const __hip_bfloat16* g = Abf + (int64_t)(bm * 128 + wave * 32 + grow) * K + k0 + gcolsw;
#pragma unroll
            for (int t = 0; t < 4; t++)
                glds16(g + (int64_t)(t * 8) * K, &lA[(wave * 32 + t * 8) * 64]);
        }
        if (BBF) {
            const __hip_bfloat16* g = (const __hip_bfloat16*)B +
                (int64_t)(bn * 64 + wave * 16 + grow) * K + k0 + gcolsw;
#pragma unroll
            for (int t = 0; t < 2; t++)
                glds16(g + (int64_t)(t * 8) * K, &lB[(wave * 16 + t * 8) * 64]);
        } else {
#pragma unroll
            for (int t = 0; t < 2; t++) {
                const int r = t * 32 + srow;
                *(short8*)&lB[r * 64 + (scol ^ ((r & 7) * 8))] = rb[t];
            }
        }
        __syncthreads();

#pragma unroll
        for (int kk = 0; kk < 2; kk++) {
            const int ksw = (kk * 32 + quad * 8) ^ ((m16 & 7) * 8);
            short8 af[4], bf[2];
#pragma unroll
            for (int i = 0; i < 4; i++)
                af[i] = *(const short8*)&lA[(wm + i * 16 + m16) * 64 + ksw];
#pragma unroll
            for (int j = 0; j < 2; j++)
                bf[j] = *(const short8*)&lB[(wn + j * 16 + m16) * 64 + ksw];
#pragma unroll
            for (int i = 0; i < 4; i++)
#pragma unroll
                for (int j = 0; j < 2; j++)
                    acc[i][j] = MFMA16(af[i], bf[j], acc[i][j]);
        }
    }

    const int row0 = bm * 128 + wm + quad * 4;
    const int col0 = bn * 64 + wn + m16;
#pragma unroll
    for (int i = 0; i < 4; i++)
#pragma unroll
        for (int j = 0; j < 2; j++)
#pragma unroll
            for (int r = 0; r < 4; r++)
                C[(int64_t)(row0 + i * 16 + r) * N + col0 + j * 16] = acc[i][j][r];
}

// ---------------------------------------------------------------------------
// Flash attention, causal, fixed-max softmax (Q pre-scaled by log2e/8;
// p = exp2(score) via RAW v_exp_f32). Block = 4 waves x 32 Q rows = 128;
// Bc = 64. S^T-MFMA: st[mi][ni] = MFMA(K-frag, Q-frag) gives S^T in
// C-layout -> pk2 + ds_write_b64 into lP (XOR swizzle key, r-invariant).
// PV reads lP with the proven 0-conflict b128 pattern. lsum VALU-accumulated
// per (ni, m16); epilogue: 2 shuffles + shfl-gather of 1/l. VGPR 76,
// 5 blocks/CU (grid 1024 fully resident at 4/CU).
// ---------------------------------------------------------------------------
__global__ __launch_bounds__(256) void attn_kernel(
    const __hip_bfloat16* __restrict__ Q,
    const __hip_bfloat16* __restrict__ Kg,
    const __hip_bfloat16* __restrict__ Vt,
    __hip_bfloat16* __restrict__ O,
    int S, int BS)
{
    // g -> qt permutation: residency groups {x, x+4, x+8, x+12} each sum to
    // 30 kt-units -> per-CU balanced; heavy blocks first. bh stays bid&63 so
    // all qt-blocks of one (b,h) keep sharing an XCD (K/V L2-local).
    const int g = blockIdx.x >> 6;        // 0..15 (S=2048)
    const int qt = (g < 4) ? 15 - g : (g < 8) ? 11 - g : (g < 12) ? g : g - 12;
    const int bh = blockIdx.x & 63;
    const int b = bh >> 4, h = bh & 15;
    const int tid = threadIdx.x;
    const int wave = tid >> 6, lane = tid & 63;
    const int m16 = lane & 15, quad = lane >> 4;

    __shared__ __hip_bfloat16 lK[64 * 64];
    __shared__ __hip_bfloat16 lV[64 * 64];        // Vt tile: [d][kv]
    __shared__ __hip_bfloat16 lP[4][32 * 64];     // total LDS = 32768 B

    const int qrow0 = qt * 128 + wave * 32;
    const int64_t rowbase = (int64_t)b * S;

    // Q frags (B-operand of the S^T MFMA): aq[ni][ks]
    short8 aq[2][2];
#pragma unroll
    for (int i = 0; i < 2; i++) {
        const __hip_bfloat16* qp = Q + (rowbase + qrow0 + i * 16 + m16) * 1024 + h * 64 + quad * 8;
        aq[i][0] = *(const short8*)qp;
        aq[i][1] = *(const short8*)(qp + 32);
    }

    float lsum[2] = {0.f, 0.f};                   // per (ni, lane m16) partials
    float4v o_acc[2][4] = {};

    const int srow = tid >> 3;
    const int scol = (tid & 7) * 8;

    const int ktmax_blk = 2 * qt + 1;
    const int ktmax_w = 2 * qt + (wave >> 1);
    const int k8 = (m16 & 7) * 8;                 // lP swizzle key (elems)

    short8 pk0, pk1, pv0, pv1;
#define PREFETCH(KT)                                                                          \
    do {                                                                                      \
        pk0 = *(const short8*)(Kg + (rowbase + (KT) * 64 + srow) * 1024 + h * 64 + scol);     \
        pk1 = *(const short8*)(Kg + (rowbase + (KT) * 64 + srow + 32) * 1024 + h * 64 + scol);\
        pv0 = *(const short8*)(Vt + (int64_t)(h * 64 + srow) * BS + rowbase + (KT) * 64 + scol);      \
        pv1 = *(const short8*)(Vt + (int64_t)(h * 64 + srow + 32) * BS + rowbase + (KT) * 64 + scol); \
    } while (0)

    PREFETCH(0);

    for (int kt = 0; kt <= ktmax_blk; kt++) {
        __syncthreads();
        *(short8*)&lK[srow * 64 + (scol ^ ((srow & 7) * 8))] = pk0;
        *(short8*)&lK[(srow + 32) * 64 + (scol ^ (((srow + 32) & 7) * 8))] = pk1;
        *(short8*)&lV[srow * 64 + (scol ^ ((srow & 7) * 8))] = pv0;
        *(short8*)&lV[(srow + 32) * 64 + (scol ^ (((srow + 32) & 7) * 8))] = pv1;
        __syncthreads();

        if (kt < ktmax_blk) PREFETCH(kt + 1);

        if (kt <= ktmax_w) {
            // S^T = K Q^T : st[mi][ni], C-layout row = kv, col = qrow
            float4v st[4][2] = {};
#pragma unroll
            for (int mi = 0; mi < 4; mi++) {
                const int n = mi * 16 + m16;
                const int sw = (n & 7) * 8;
                short8 k0 = *(const short8*)&lK[n * 64 + ((quad * 8) ^ sw)];
                short8 k1 = *(const short8*)&lK[n * 64 + ((32 + quad * 8) ^ sw)];
#pragma unroll
                for (int ni = 0; ni < 2; ni++) {
                    st[mi][ni] = MFMA16(k0, aq[ni][0], st[mi][ni]);
                    st[mi][ni] = MFMA16(k1, aq[ni][1], st[mi][ni]);
                }
            }

            // exp2 (raw v_exp_f32), causal mask, lsum, packed b64 write to lP
            const bool need_mask = (kt * 64 + 63 > qrow0);
#pragma unroll
            for (int ni = 0; ni < 2; ni++) {
                const int qg = qrow0 + ni * 16 + m16;
#pragma unroll
                for (int mi = 0; mi < 4; mi++) {
                    float p[4];
#pragma unroll
                    for (int r = 0; r < 4; r++) {
                        p[r] = __builtin_amdgcn_exp2f(st[mi][ni][r]);
                        if (need_mask) {
                            const int kvg = kt * 64 + mi * 16 + quad * 4 + r;
                            if (kvg > qg) p[r] = 0.0f;
                        }
                    }
                    lsum[ni] += (p[0] + p[1]) + (p[2] + p[3]);
                    uint2 w;
                    w.x = pk2(p[0], p[1]);
                    w.y = pk2(p[2], p[3]);
                    *(uint2*)&lP[wave][(ni * 16 + m16) * 64 + ((mi * 16 + quad * 4) ^ k8)] = w;
                }
            }

            // O += P V (lP wave-private; lgkmcnt ordering suffices)
            short8 ap[2][2];
#pragma unroll
            for (int i = 0; i < 2; i++)
#pragma unroll
                for (int ks = 0; ks < 2; ks++)
                    ap[i][ks] = *(const short8*)
                        &lP[wave][(i * 16 + m16) * 64 + ((ks * 32 + quad * 8) ^ k8)];
#pragma unroll
            for (int jd = 0; jd < 4; jd++) {
                const int d = jd * 16 + m16;
                const int sw = (d & 7) * 8;
                short8 b0 = *(const short8*)&lV[d * 64 + ((quad * 8) ^ sw)];
                short8 b1 = *(const short8*)&lV[d * 64 + ((32 + quad * 8) ^ sw)];
#pragma unroll
                for (int i = 0; i < 2; i++) {
                    o_acc[i][jd] = MFMA16(ap[i][0], b0, o_acc[i][jd]);
                    o_acc[i][jd] = MFMA16(ap[i][1], b1, o_acc[i][jd]);
                }
            }
        }
    }
#undef PREFETCH

    // l reduction: after xor16+xor32 every lane holds its m16-column's full
    // sum; invert once, then shfl-gather 1/l for the O-store lanes (no LDS).
    float rinv[2];
#pragma unroll
    for (int ni = 0; ni < 2; ni++) {
        float v = lsum[ni];
        v += __shfl_xor(v, 16);
        v += __shfl_xor(v, 32);
        rinv[ni] = 1.0f / v;
    }
    float ri[2][4];
#pragma unroll
    for (int i = 0; i < 2; i++)
#pragma unroll
        for (int r = 0; r < 4; r++)
            ri[i][r] = __shfl(rinv[i], quad * 4 + r);   // lane p holds column p

#pragma unroll
    for (int i = 0; i < 2; i++)
#pragma unroll
        for (int jd = 0; jd < 4; jd++)
#pragma unroll
            for (int r = 0; r < 4; r++) {
                const int row = qrow0 + i * 16 + quad * 4 + r;
                O[(rowbase + row) * 1024 + h * 64 + jd * 16 + m16] =
                    __float2bfloat16(o_acc[i][jd][r] * ri[i][r]);
            }
}

// ---------------------------------------------------------------------------
extern "C" void kernel_launch(void* const* d_in, const int* in_sizes, int n_in,
                              void* d_out, int out_size, void* d_ws, size_t ws_size,
                              hipStream_t stream)
{
    const float* x  = (const float*)d_in[0];
    const float* qw = (const float*)d_in[1];
    const float* kw = (const float*)d_in[2];
    const float* vw = (const float*)d_in[3];
    const float* ow = (const float*)d_in[4];

    const int BS = 8192, D = 1024, S = 2048;
    const size_t MiB = 1024 * 1024;

    char* ws = (char*)d_ws;
    __hip_bfloat16* xb  = (__hip_bfloat16*)(ws);
    __hip_bfloat16* Qb  = (__hip_bfloat16*)(ws + 16 * MiB); // also AO
    __hip_bfloat16* Kb  = (__hip_bfloat16*)(ws + 32 * MiB);
    __hip_bfloat16* Vtb = (__hip_bfloat16*)(ws + 48 * MiB);
    __hip_bfloat16* wqb = (__hip_bfloat16*)(ws + 64 * MiB);
    __hip_bfloat16* wkb = (__hip_bfloat16*)(ws + 66 * MiB);
    __hip_bfloat16* wvb = (__hip_bfloat16*)(ws + 68 * MiB);
    __hip_bfloat16* wob = (__hip_bfloat16*)(ws + 70 * MiB);
    // rope table lives in d_out's tail (512 KB at +31 MiB): written by
    // convert_x_table, read by qkv_gemm, dead before gemm_o overwrites d_out.
    float2* table = (float2*)((char*)d_out + 31 * MiB);
    const bool wbf = ws_size >= 72 * MiB;                   // fast path fits?

    dim3 blk(256);
    convert_x_table<<<4096 + 256, blk, 0, stream>>>(x, xb, table);
    if (wbf) {
        convert4_kernel<<<4 * (D * D) / 2048, blk, 0, stream>>>(
            qw, kw, vw, ow, wqb, wkb, wvb, wob);
        qkv_gemm<1><<<64 * 48, blk, 0, stream>>>(xb, wqb, wkb, wvb, Qb, Kb, Vtb, table);
    } else {
        qkv_gemm<0><<<64 * 48, blk, 0, stream>>>(xb, qw, kw, vw, Qb, Kb, Vtb, table);
    }
    attn_kernel<<<4 * 16 * (S / 128), blk, 0, stream>>>(Qb, Kb, Vtb, Qb /*AO*/, S, BS);
    if (wbf) gemm_o<1><<<(BS / 128) * (D / 64), blk, 0, stream>>>(Qb, wob, (float*)d_out, BS, D, D);
    else     gemm_o<0><<<(BS / 128) * (D / 64), blk, 0, stream>>>(Qb, ow,  (float*)d_out, BS, D, D);
}